// Round 2
// baseline (485.658 us; speedup 1.0000x reference)
//
#include <hip/hip_runtime.h>
#include <math.h>

// ============================================================================
// GeoTransformer head — MI355X fp32 baseline (round 1: resubmit — round 0
// never ran, GPU broker at capacity; desk-checked, no changes)
//
// Algebraic shortcuts vs reference:
//  - fms = rf@sf.T never materialized: only 16384 gathered dot products needed.
//  - h3 GEMM (16384x512x1024) eliminated: pooled = colmean(h2r) @ W3 + b3.
//  - dist matrix never materialized: fused min/argmin passes.
//
// ws layout (floats), total 25,905,152 floats = ~98.8 MiB
// ============================================================================

#define NREF 8192
#define NSRC 8192
#define NTOT 16384
#define DF   256
#define DCAT 520
#define EPSV 1e-5f

#define OFF_RF    0u
#define OFF_SF    2097152u
#define OFF_PTSN  4194304u
#define OFF_PMIN  4243456u
#define OFF_PIDX  4505600u
#define OFF_IDX   4767744u
#define OFF_MD    4784128u
#define OFF_FEAT  4800512u
#define OFF_H1    13320192u
#define OFF_H2    17514496u
#define OFF_MBAR  25903104u
#define OFF_POOL  25903616u
#define OFF_T1    25904640u

// ---------------------------------------------------------------- reductions
__device__ __forceinline__ float block_reduce_sum(float v, float* sm) {
    int t = threadIdx.x;
    sm[t] = v; __syncthreads();
    for (int s = 128; s > 0; s >>= 1) {
        if (t < s) sm[t] += sm[t + s];
        __syncthreads();
    }
    float r = sm[0]; __syncthreads();
    return r;
}

__device__ __forceinline__ float block_reduce_max(float v, float* sm) {
    int t = threadIdx.x;
    sm[t] = v; __syncthreads();
    for (int s = 128; s > 0; s >>= 1) {
        if (t < s) sm[t] = fmaxf(sm[t], sm[t + s]);
        __syncthreads();
    }
    float r = sm[0]; __syncthreads();
    return r;
}

// ---------------------------------------------------------------- 1. l2norm
// grid 16384 blocks x 256: rows 0..8191 -> rf, 8192.. -> sf
__global__ __launch_bounds__(256) void l2norm_kernel(
    const float* __restrict__ rfeat, const float* __restrict__ sfeat,
    float* __restrict__ rf, float* __restrict__ sf) {
    __shared__ float sm[256];
    int i = blockIdx.x, t = threadIdx.x;
    const float* in; float* out;
    if (i < NREF) { in = rfeat + (size_t)i * DF;          out = rf + (size_t)i * DF; }
    else          { in = sfeat + (size_t)(i - NREF) * DF; out = sf + (size_t)(i - NREF) * DF; }
    float x = in[t];
    float ss = block_reduce_sum(x * x, sm);
    float nrm = fmaxf(sqrtf(ss), 1e-12f);
    out[t] = x / nrm;
}

// ---------------------------------------------------------------- 2. points norm
// single block: mean over 16384 pts, subtract, /max-norm. ptsn[0:8192)=ref.
__global__ __launch_bounds__(256) void pts_norm_kernel(
    const float* __restrict__ rp, const float* __restrict__ sp,
    float* __restrict__ ptsn) {
    __shared__ float sm[256];
    __shared__ float s_mean[3];
    __shared__ float s_R;
    int t = threadIdx.x;
    float sx = 0.f, sy = 0.f, sz = 0.f;
    for (int i = t; i < NTOT; i += 256) {
        const float* p = (i < NREF) ? (rp + 3 * i) : (sp + 3 * (i - NREF));
        sx += p[0]; sy += p[1]; sz += p[2];
    }
    sx = block_reduce_sum(sx, sm);
    sy = block_reduce_sum(sy, sm);
    sz = block_reduce_sum(sz, sm);
    if (t == 0) {
        s_mean[0] = sx * (1.0f / NTOT);
        s_mean[1] = sy * (1.0f / NTOT);
        s_mean[2] = sz * (1.0f / NTOT);
    }
    __syncthreads();
    float mx = s_mean[0], my = s_mean[1], mz = s_mean[2];
    float vmax = 0.f;
    for (int i = t; i < NTOT; i += 256) {
        const float* p = (i < NREF) ? (rp + 3 * i) : (sp + 3 * (i - NREF));
        float dx = p[0] - mx, dy = p[1] - my, dz = p[2] - mz;
        vmax = fmaxf(vmax, dx * dx + dy * dy + dz * dz);
    }
    vmax = block_reduce_max(vmax, sm);
    if (t == 0) s_R = sqrtf(vmax);
    __syncthreads();
    float R = s_R;
    for (int i = t; i < NTOT; i += 256) {
        const float* p = (i < NREF) ? (rp + 3 * i) : (sp + 3 * (i - NREF));
        ptsn[3 * i + 0] = (p[0] - mx) / R;
        ptsn[3 * i + 1] = (p[1] - my) / R;
        ptsn[3 * i + 2] = (p[2] - mz) / R;
    }
}

// ---------------------------------------------------------------- 3. NN partial
// grid (32, 16, 2), block 256. z=0: queries=ref targets=src; z=1: swapped.
// Each block: 256 queries x 512-target slice; strict < keeps first argmin.
__global__ __launch_bounds__(256) void dist_partial_kernel(
    const float* __restrict__ rp, const float* __restrict__ sp,
    float* __restrict__ pmin, int* __restrict__ pidx) {
    __shared__ float4 tg[512];
    int pass = blockIdx.z;
    const float* Q = pass ? sp : rp;
    const float* T = pass ? rp : sp;
    int t = threadIdx.x;
    int j0 = blockIdx.y * 512;
    for (int k = t; k < 512; k += 256) {
        float x = T[3 * (j0 + k) + 0];
        float y = T[3 * (j0 + k) + 1];
        float z = T[3 * (j0 + k) + 2];
        tg[k] = make_float4(x, y, z, x * x + y * y + z * z);
    }
    __syncthreads();
    int qid = blockIdx.x * 256 + t;
    float qx = Q[3 * qid + 0], qy = Q[3 * qid + 1], qz = Q[3 * qid + 2];
    float rr = qx * qx + qy * qy + qz * qz;
    float best = 3.4e38f; int bj = 0;
    #pragma unroll 4
    for (int j = 0; j < 512; ++j) {
        float4 f = tg[j];
        float dot = qx * f.x + qy * f.y + qz * f.z;
        float d2 = rr + f.w - 2.0f * dot;
        if (d2 < best) { best = d2; bj = j; }
    }
    int slot = ((pass << 4) + blockIdx.y) * 8192 + qid;
    pmin[slot] = best;
    pidx[slot] = j0 + bj;
}

// ---------------------------------------------------------------- 4. NN reduce
// 16384 threads: fold 16 split partials in order (strict <), emit idx + dist.
__global__ __launch_bounds__(256) void dist_reduce_kernel(
    const float* __restrict__ pmin, const int* __restrict__ pidx,
    int* __restrict__ idx, float* __restrict__ md) {
    int gid = blockIdx.x * 256 + threadIdx.x;
    int pass = gid >> 13;
    int q = gid & 8191;
    float best = 3.4e38f; int bi = 0;
    #pragma unroll
    for (int s = 0; s < 16; ++s) {
        int slot = ((pass << 4) + s) * 8192 + q;
        float v = pmin[slot];
        if (v < best) { best = v; bi = pidx[slot]; }
    }
    idx[pass * 8192 + q] = bi;
    md[pass * 8192 + q] = sqrtf(fmaxf(best, 1e-12f));
}

// ---------------------------------------------------------------- 5. feat assembly
// grid 16384 x 256. Row layout: [fa(256) | fb(256) | pa(3) | pb(3) | dist | score]
__global__ __launch_bounds__(256) void feat_assemble_kernel(
    const float* __restrict__ rf, const float* __restrict__ sf,
    const float* __restrict__ ptsn, const int* __restrict__ idx,
    const float* __restrict__ md, float* __restrict__ feat) {
    __shared__ float sm[256];
    int i = blockIdx.x, t = threadIdx.x;
    const float *fa, *fb, *pa, *pb; float dist;
    if (i < NREF) {
        int j = idx[i];
        fa = rf + (size_t)i * DF;  fb = sf + (size_t)j * DF;
        pa = ptsn + 3 * i;         pb = ptsn + 3 * (NREF + j);
        dist = md[i];
    } else {
        int jj = i - NREF;
        int j = idx[NREF + jj];
        fa = sf + (size_t)jj * DF; fb = rf + (size_t)j * DF;
        pa = ptsn + 3 * (NREF + jj); pb = ptsn + 3 * j;
        dist = md[NREF + jj];
    }
    float a = fa[t], b = fb[t];
    float* fr = feat + (size_t)i * DCAT;
    fr[t] = a;
    fr[DF + t] = b;
    float sc = block_reduce_sum(a * b, sm);
    if (t < 3) {
        fr[512 + t] = pa[t];
        fr[515 + t] = pb[t];
    }
    if (t == 0) { fr[518] = dist; fr[519] = sc; }
}

// ---------------------------------------------------------------- 6. SGEMM+bias
// C[M,N] = A[M,K] @ B[K,N] + bias. 128x128 tile, 256 thr, 8x8 microtile, BK=8.
#define BM 128
#define BN 128
#define BK 8
__global__ __launch_bounds__(256) void sgemm_bias_kernel(
    const float* __restrict__ A, const float* __restrict__ B,
    const float* __restrict__ bias, float* __restrict__ C,
    int M, int N, int K) {
    __shared__ float As[BK][BM];
    __shared__ float Bs[BK][BN];
    int row0 = blockIdx.x * BM, col0 = blockIdx.y * BN;
    int tid = threadIdx.x;
    int ty = tid >> 4, tx = tid & 15;
    int arow = tid >> 1, acol = (tid & 1) * 4;
    int brow = tid >> 5, bcol = (tid & 31) * 4;

    float4 aR = *(const float4*)&A[(size_t)(row0 + arow) * K + acol];
    float4 bR = *(const float4*)&B[(size_t)brow * N + col0 + bcol];

    float acc[8][8];
    #pragma unroll
    for (int i = 0; i < 8; ++i)
        #pragma unroll
        for (int j = 0; j < 8; ++j) acc[i][j] = 0.f;

    int ktiles = K / BK;
    for (int kt = 0; kt < ktiles; ++kt) {
        As[acol + 0][arow] = aR.x;
        As[acol + 1][arow] = aR.y;
        As[acol + 2][arow] = aR.z;
        As[acol + 3][arow] = aR.w;
        *(float4*)&Bs[brow][bcol] = bR;
        __syncthreads();
        if (kt + 1 < ktiles) {
            int k0n = (kt + 1) * BK;
            aR = *(const float4*)&A[(size_t)(row0 + arow) * K + k0n + acol];
            bR = *(const float4*)&B[(size_t)(k0n + brow) * N + col0 + bcol];
        }
        #pragma unroll
        for (int kk = 0; kk < BK; ++kk) {
            float a[8], b[8];
            *(float4*)&a[0] = *(const float4*)&As[kk][ty * 8];
            *(float4*)&a[4] = *(const float4*)&As[kk][ty * 8 + 4];
            *(float4*)&b[0] = *(const float4*)&Bs[kk][tx * 8];
            *(float4*)&b[4] = *(const float4*)&Bs[kk][tx * 8 + 4];
            #pragma unroll
            for (int i = 0; i < 8; ++i)
                #pragma unroll
                for (int j = 0; j < 8; ++j)
                    acc[i][j] = fmaf(a[i], b[j], acc[i][j]);
        }
        __syncthreads();
    }

    float bj[8];
    #pragma unroll
    for (int j = 0; j < 8; ++j) bj[j] = bias[col0 + tx * 8 + j];
    #pragma unroll
    for (int i = 0; i < 8; ++i) {
        int r = row0 + ty * 8 + i;
        float* crow = C + (size_t)r * N + col0 + tx * 8;
        float4 o0, o1;
        o0.x = acc[i][0] + bj[0]; o0.y = acc[i][1] + bj[1];
        o0.z = acc[i][2] + bj[2]; o0.w = acc[i][3] + bj[3];
        o1.x = acc[i][4] + bj[4]; o1.y = acc[i][5] + bj[5];
        o1.z = acc[i][6] + bj[6]; o1.w = acc[i][7] + bj[7];
        *(float4*)&crow[0] = o0;
        *(float4*)&crow[4] = o1;
    }
}

// ---------------------------------------------------------------- 7. instnorm+relu
template <int C>
__global__ __launch_bounds__(256) void inst_norm_relu_kernel(float* __restrict__ h) {
    __shared__ float sm[256];
    constexpr int NE = C / 256;
    float* row = h + (size_t)blockIdx.x * C;
    int t = threadIdx.x;
    float x[NE];
    float s = 0.f;
    #pragma unroll
    for (int e = 0; e < NE; ++e) { x[e] = row[t + 256 * e]; s += x[e]; }
    s = block_reduce_sum(s, sm);
    float m = s * (1.0f / C);
    float q = 0.f;
    #pragma unroll
    for (int e = 0; e < NE; ++e) { x[e] -= m; q += x[e] * x[e]; }
    q = block_reduce_sum(q, sm);
    float rs = rsqrtf(q * (1.0f / C) + EPSV);
    #pragma unroll
    for (int e = 0; e < NE; ++e) row[t + 256 * e] = fmaxf(x[e] * rs, 0.f);
}

// ---------------------------------------------------------------- 8. column sum
// grid 128 x 256: each block sums 128 rows of h2r (16384x512) -> atomicAdd
__global__ __launch_bounds__(256) void colsum_kernel(
    const float* __restrict__ h2, float* __restrict__ mbar) {
    int t = threadIdx.x;
    int r0 = blockIdx.x * 128;
    float s0 = 0.f, s1 = 0.f;
    for (int r = 0; r < 128; ++r) {
        const float* row = h2 + (size_t)(r0 + r) * 512;
        s0 += row[t];
        s1 += row[t + 256];
    }
    atomicAdd(&mbar[t], s0);
    atomicAdd(&mbar[t + 256], s1);
}

// ---------------------------------------------------------------- 9. pooled = colmean @ W3 + b3
__global__ __launch_bounds__(256) void pooled_mv_kernel(
    const float* __restrict__ mbar, const float* __restrict__ W3,
    const float* __restrict__ b3, float* __restrict__ pooled) {
    int j = blockIdx.x * 256 + threadIdx.x;   // < 1024
    float acc = 0.f;
    for (int k = 0; k < 512; ++k) acc = fmaf(mbar[k], W3[k * 1024 + j], acc);
    pooled[j] = acc * (1.0f / 16384.0f) + b3[j];
}

// ---------------------------------------------------------------- 10. c1 matvec
__global__ __launch_bounds__(256) void c1_mv_kernel(
    const float* __restrict__ pooled, const float* __restrict__ Wc1,
    const float* __restrict__ bc1, float* __restrict__ t1) {
    int o = blockIdx.x * 256 + threadIdx.x;   // < 512
    float acc = bc1[o];
    for (int k = 0; k < 1024; ++k) acc = fmaf(pooled[k], Wc1[k * 512 + o], acc);
    t1[o] = acc;
}

// ---------------------------------------------------------------- 11. tail
// single block 256 thr: GN1(512,g16)+relu -> c2 matvec -> GN2(256,g8)+relu -> out(2)
__global__ __launch_bounds__(256) void tail_kernel(
    const float* __restrict__ t1, const float* __restrict__ g1, const float* __restrict__ be1,
    const float* __restrict__ Wc2, const float* __restrict__ bc2,
    const float* __restrict__ g2, const float* __restrict__ be2,
    const float* __restrict__ Wc3, const float* __restrict__ bc3,
    float* __restrict__ out) {
    __shared__ float a1[512];
    __shared__ float a2[256];
    __shared__ float gm[32], gv[32];
    int t = threadIdx.x;
    a1[t] = t1[t];
    a1[t + 256] = t1[t + 256];
    __syncthreads();
    if (t < 32) {
        float s = 0.f;
        for (int k = 0; k < 16; ++k) s += a1[t * 16 + k];
        float m = s * (1.0f / 16.0f);
        float q = 0.f;
        for (int k = 0; k < 16; ++k) { float d = a1[t * 16 + k] - m; q += d * d; }
        gm[t] = m;
        gv[t] = rsqrtf(q * (1.0f / 16.0f) + EPSV);
    }
    __syncthreads();
    float v0 = (a1[t] - gm[t >> 4]) * gv[t >> 4];
    float v1 = (a1[t + 256] - gm[(t + 256) >> 4]) * gv[(t + 256) >> 4];
    v0 = fmaxf(fmaf(v0, g1[t], be1[t]), 0.f);
    v1 = fmaxf(fmaf(v1, g1[t + 256], be1[t + 256]), 0.f);
    __syncthreads();
    a1[t] = v0;
    a1[t + 256] = v1;
    __syncthreads();
    // c2 = a1 @ Wc2 + bc2  (o = t < 256)
    float acc = bc2[t];
    for (int k = 0; k < 512; ++k) acc = fmaf(a1[k], Wc2[k * 256 + t], acc);
    a2[t] = acc;
    __syncthreads();
    if (t < 32) {
        float s = 0.f;
        for (int k = 0; k < 8; ++k) s += a2[t * 8 + k];
        float m = s * (1.0f / 8.0f);
        float q = 0.f;
        for (int k = 0; k < 8; ++k) { float d = a2[t * 8 + k] - m; q += d * d; }
        gm[t] = m;
        gv[t] = rsqrtf(q * (1.0f / 8.0f) + EPSV);
    }
    __syncthreads();
    float w = (a2[t] - gm[t >> 3]) * gv[t >> 3];
    w = fmaxf(fmaf(w, g2[t], be2[t]), 0.f);
    __syncthreads();
    a2[t] = w;
    __syncthreads();
    if (t < 2) {
        float acc2 = bc3[t];
        for (int k = 0; k < 256; ++k) acc2 = fmaf(a2[k], Wc3[k * 2 + t], acc2);
        out[t] = acc2;
    }
}

// ============================================================================
extern "C" void kernel_launch(void* const* d_in, const int* in_sizes, int n_in,
                              void* d_out, int out_size, void* d_ws, size_t ws_size,
                              hipStream_t stream) {
    const float* ref_points = (const float*)d_in[0];
    const float* src_points = (const float*)d_in[1];
    const float* ref_feats  = (const float*)d_in[2];
    const float* src_feats  = (const float*)d_in[3];
    const float* W1  = (const float*)d_in[4];
    const float* b1  = (const float*)d_in[5];
    const float* W2  = (const float*)d_in[6];
    const float* b2  = (const float*)d_in[7];
    const float* W3  = (const float*)d_in[8];
    const float* b3  = (const float*)d_in[9];
    const float* Wc1 = (const float*)d_in[10];
    const float* bc1 = (const float*)d_in[11];
    const float* g1  = (const float*)d_in[12];
    const float* be1 = (const float*)d_in[13];
    const float* Wc2 = (const float*)d_in[14];
    const float* bc2 = (const float*)d_in[15];
    const float* g2  = (const float*)d_in[16];
    const float* be2 = (const float*)d_in[17];
    const float* Wc3 = (const float*)d_in[18];
    const float* bc3 = (const float*)d_in[19];
    float* out = (float*)d_out;

    float* ws   = (float*)d_ws;
    float* rf   = ws + OFF_RF;
    float* sf   = ws + OFF_SF;
    float* ptsn = ws + OFF_PTSN;
    float* pmin = ws + OFF_PMIN;
    int*   pidx = (int*)(ws + OFF_PIDX);
    int*   idx  = (int*)(ws + OFF_IDX);
    float* md   = ws + OFF_MD;
    float* feat = ws + OFF_FEAT;
    float* h1   = ws + OFF_H1;
    float* h2   = ws + OFF_H2;
    float* mbar = ws + OFF_MBAR;
    float* pool = ws + OFF_POOL;
    float* t1   = ws + OFF_T1;

    hipLaunchKernelGGL(l2norm_kernel, dim3(NTOT), dim3(256), 0, stream,
                       ref_feats, src_feats, rf, sf);
    hipLaunchKernelGGL(pts_norm_kernel, dim3(1), dim3(256), 0, stream,
                       ref_points, src_points, ptsn);
    hipLaunchKernelGGL(dist_partial_kernel, dim3(32, 16, 2), dim3(256), 0, stream,
                       ref_points, src_points, pmin, pidx);
    hipLaunchKernelGGL(dist_reduce_kernel, dim3(64), dim3(256), 0, stream,
                       pmin, pidx, idx, md);
    hipLaunchKernelGGL(feat_assemble_kernel, dim3(NTOT), dim3(256), 0, stream,
                       rf, sf, ptsn, idx, md, feat);
    hipLaunchKernelGGL(sgemm_bias_kernel, dim3(128, 2), dim3(256), 0, stream,
                       feat, W1, b1, h1, 16384, 256, 520);
    hipLaunchKernelGGL(inst_norm_relu_kernel<256>, dim3(NTOT), dim3(256), 0, stream, h1);
    hipLaunchKernelGGL(sgemm_bias_kernel, dim3(128, 4), dim3(256), 0, stream,
                       h1, W2, b2, h2, 16384, 512, 256);
    hipLaunchKernelGGL(inst_norm_relu_kernel<512>, dim3(NTOT), dim3(256), 0, stream, h2);
    hipMemsetAsync(mbar, 0, 512 * sizeof(float), stream);
    hipLaunchKernelGGL(colsum_kernel, dim3(128), dim3(256), 0, stream, h2, mbar);
    hipLaunchKernelGGL(pooled_mv_kernel, dim3(4), dim3(256), 0, stream, mbar, W3, b3, pool);
    hipLaunchKernelGGL(c1_mv_kernel, dim3(2), dim3(256), 0, stream, pool, Wc1, bc1, t1);
    hipLaunchKernelGGL(tail_kernel, dim3(1), dim3(256), 0, stream,
                       t1, g1, be1, Wc2, bc2, g2, be2, Wc3, bc3, out);
}

// Round 3
// 355.259 us; speedup vs baseline: 1.3671x; 1.3671x over previous
//
#include <hip/hip_runtime.h>
#include <math.h>

// ============================================================================
// GeoTransformer head — round 3: split-bf16 MFMA GEMMs + parallelized tail
//
//  - GEMM1/2 as plain bf16 MFMA GEMM with K'=3K (A'=[Ahi|Ahi|Alo],
//    B'^T=[Bhi|Blo|Bhi]): fp32-class accuracy (~1e-4 rel), MFMA speed.
//  - K1 padded 520->544 (B' pad rows zeroed so A pad content is ignored).
//  - inst_norm<512>+colsum fused (saves 67MB round trip).
//  - pooled_mv / c1_mv k-split across blocks + atomicAdd (was 4/2 blocks,
//    latency-serialized); biases folded into consumers.
//
// ws layout (float units), total 22,771,712 floats = 86.9 MiB:
//  [0 .. 18,169,856)  UNION region:
//    phase1: rf@0, sf@2097152, ptsn@4194304, pmin@4243456, pidx@4505600,
//            idx@4767744, md@4784128  (ends 4,800,512)
//            A1'(ushort)@4,800,512 .. 18,169,856  (16384x1632 bf16)
//    phase2: A2'(ushort)@0 .. 6,291,456           (16384x768 bf16)
//    phase3: h2(f32)@6,291,456 .. 14,680,064      (16384x512)
//  W1T'@18,169,856  W2T'@18,378,752  h1@18,575,360
//  zero-region@22,769,664: mbar[512] pool_raw[1024] t1_raw[512]
// ============================================================================

#define NREF 8192
#define NSRC 8192
#define NTOT 16384
#define DF   256
#define EPSV 1e-5f

#define K1P  544
#define K1X  1632   // 3*K1P
#define K2X  768    // 3*256

#define OFF_RF    0u
#define OFF_SF    2097152u
#define OFF_PTSN  4194304u
#define OFF_PMIN  4243456u
#define OFF_PIDX  4505600u
#define OFF_IDX   4767744u
#define OFF_MD    4784128u
#define OFF_A1    4800512u
#define OFF_A2    0u
#define OFF_H2    6291456u
#define OFF_W1T   18169856u
#define OFF_W2T   18378752u
#define OFF_H1    18575360u
#define OFF_ZERO  22769664u   // mbar(512) pool_raw(1024) t1_raw(512)

typedef float f32x4 __attribute__((ext_vector_type(4)));
typedef __bf16 bf16x8 __attribute__((ext_vector_type(8)));

// ---------------------------------------------------------------- bf16 split
__device__ __forceinline__ unsigned short f2bf_rn(float x) {
    union { float f; unsigned int u; } v; v.f = x;
    unsigned int r = (v.u + 0x7FFFu + ((v.u >> 16) & 1u)) >> 16;
    return (unsigned short)r;
}
__device__ __forceinline__ float bf2f(unsigned short h) {
    union { unsigned int u; float f; } v; v.u = ((unsigned int)h) << 16;
    return v.f;
}

// ---------------------------------------------------------------- reductions
__device__ __forceinline__ float block_reduce_sum(float v, float* sm) {
    int t = threadIdx.x;
    sm[t] = v; __syncthreads();
    for (int s = 128; s > 0; s >>= 1) {
        if (t < s) sm[t] += sm[t + s];
        __syncthreads();
    }
    float r = sm[0]; __syncthreads();
    return r;
}
__device__ __forceinline__ float block_reduce_max(float v, float* sm) {
    int t = threadIdx.x;
    sm[t] = v; __syncthreads();
    for (int s = 128; s > 0; s >>= 1) {
        if (t < s) sm[t] = fmaxf(sm[t], sm[t + s]);
        __syncthreads();
    }
    float r = sm[0]; __syncthreads();
    return r;
}

// ---------------------------------------------------------------- weight prep
// W1 [520][256] f32 -> W1T' [256][1632] bf16 ([hi | lo-pair-hi ... ] layout:
// cols [0:544)=hi, [544:1088)=LO, [1088:1632)=hi  ... matching A'=[hi|hi|lo]:
//   term1 Ahi*Bhi, term2 Ahi*Blo, term3 Alo*Bhi.
__global__ __launch_bounds__(256) void prep_w1_kernel(
    const float* __restrict__ W1, unsigned short* __restrict__ W1T) {
    int n = blockIdx.x;                 // 0..255
    unsigned short* row = W1T + (size_t)n * K1X;
    for (int k = threadIdx.x; k < K1P; k += 256) {
        unsigned short hi = 0, lo = 0;
        if (k < 520) {
            float x = W1[k * 256 + n];
            hi = f2bf_rn(x);
            lo = f2bf_rn(x - bf2f(hi));
        }
        row[k] = hi;
        row[K1P + k] = lo;      // pairs with A-section 2 (Ahi)
        row[2 * K1P + k] = hi;  // pairs with A-section 3 (Alo)
    }
}

// W2 [256][512] f32 -> W2T' [512][768] bf16
__global__ __launch_bounds__(256) void prep_w2_kernel(
    const float* __restrict__ W2, unsigned short* __restrict__ W2T) {
    int n = blockIdx.x;                 // 0..511
    int k = threadIdx.x;                // 0..255
    float x = W2[k * 512 + n];
    unsigned short hi = f2bf_rn(x);
    unsigned short lo = f2bf_rn(x - bf2f(hi));
    unsigned short* row = W2T + (size_t)n * K2X;
    row[k] = hi;
    row[256 + k] = lo;
    row[512 + k] = hi;
}

// ---------------------------------------------------------------- 1. l2norm
__global__ __launch_bounds__(256) void l2norm_kernel(
    const float* __restrict__ rfeat, const float* __restrict__ sfeat,
    float* __restrict__ rf, float* __restrict__ sf) {
    __shared__ float sm[256];
    int i = blockIdx.x, t = threadIdx.x;
    const float* in; float* out;
    if (i < NREF) { in = rfeat + (size_t)i * DF;          out = rf + (size_t)i * DF; }
    else          { in = sfeat + (size_t)(i - NREF) * DF; out = sf + (size_t)(i - NREF) * DF; }
    float x = in[t];
    float ss = block_reduce_sum(x * x, sm);
    float nrm = fmaxf(sqrtf(ss), 1e-12f);
    out[t] = x / nrm;
}

// ---------------------------------------------------------------- 2. points norm
__global__ __launch_bounds__(256) void pts_norm_kernel(
    const float* __restrict__ rp, const float* __restrict__ sp,
    float* __restrict__ ptsn) {
    __shared__ float sm[256];
    __shared__ float s_mean[3];
    __shared__ float s_R;
    int t = threadIdx.x;
    float sx = 0.f, sy = 0.f, sz = 0.f;
    for (int i = t; i < NTOT; i += 256) {
        const float* p = (i < NREF) ? (rp + 3 * i) : (sp + 3 * (i - NREF));
        sx += p[0]; sy += p[1]; sz += p[2];
    }
    sx = block_reduce_sum(sx, sm);
    sy = block_reduce_sum(sy, sm);
    sz = block_reduce_sum(sz, sm);
    if (t == 0) {
        s_mean[0] = sx * (1.0f / NTOT);
        s_mean[1] = sy * (1.0f / NTOT);
        s_mean[2] = sz * (1.0f / NTOT);
    }
    __syncthreads();
    float mx = s_mean[0], my = s_mean[1], mz = s_mean[2];
    float vmax = 0.f;
    for (int i = t; i < NTOT; i += 256) {
        const float* p = (i < NREF) ? (rp + 3 * i) : (sp + 3 * (i - NREF));
        float dx = p[0] - mx, dy = p[1] - my, dz = p[2] - mz;
        vmax = fmaxf(vmax, dx * dx + dy * dy + dz * dz);
    }
    vmax = block_reduce_max(vmax, sm);
    if (t == 0) s_R = sqrtf(vmax);
    __syncthreads();
    float R = s_R;
    for (int i = t; i < NTOT; i += 256) {
        const float* p = (i < NREF) ? (rp + 3 * i) : (sp + 3 * (i - NREF));
        ptsn[3 * i + 0] = (p[0] - mx) / R;
        ptsn[3 * i + 1] = (p[1] - my) / R;
        ptsn[3 * i + 2] = (p[2] - mz) / R;
    }
}

// ---------------------------------------------------------------- 3. NN partial
__global__ __launch_bounds__(256) void dist_partial_kernel(
    const float* __restrict__ rp, const float* __restrict__ sp,
    float* __restrict__ pmin, int* __restrict__ pidx) {
    __shared__ float4 tg[512];
    int pass = blockIdx.z;
    const float* Q = pass ? sp : rp;
    const float* T = pass ? rp : sp;
    int t = threadIdx.x;
    int j0 = blockIdx.y * 512;
    for (int k = t; k < 512; k += 256) {
        float x = T[3 * (j0 + k) + 0];
        float y = T[3 * (j0 + k) + 1];
        float z = T[3 * (j0 + k) + 2];
        tg[k] = make_float4(x, y, z, x * x + y * y + z * z);
    }
    __syncthreads();
    int qid = blockIdx.x * 256 + t;
    float qx = Q[3 * qid + 0], qy = Q[3 * qid + 1], qz = Q[3 * qid + 2];
    float rr = qx * qx + qy * qy + qz * qz;
    float best = 3.4e38f; int bj = 0;
    #pragma unroll 4
    for (int j = 0; j < 512; ++j) {
        float4 f = tg[j];
        float dot = qx * f.x + qy * f.y + qz * f.z;
        float d2 = rr + f.w - 2.0f * dot;
        if (d2 < best) { best = d2; bj = j; }
    }
    int slot = ((pass << 4) + blockIdx.y) * 8192 + qid;
    pmin[slot] = best;
    pidx[slot] = j0 + bj;
}

// ---------------------------------------------------------------- 4. NN reduce
__global__ __launch_bounds__(256) void dist_reduce_kernel(
    const float* __restrict__ pmin, const int* __restrict__ pidx,
    int* __restrict__ idx, float* __restrict__ md) {
    int gid = blockIdx.x * 256 + threadIdx.x;
    int pass = gid >> 13;
    int q = gid & 8191;
    float best = 3.4e38f; int bi = 0;
    #pragma unroll
    for (int s = 0; s < 16; ++s) {
        int slot = ((pass << 4) + s) * 8192 + q;
        float v = pmin[slot];
        if (v < best) { best = v; bi = pidx[slot]; }
    }
    idx[pass * 8192 + q] = bi;
    md[pass * 8192 + q] = sqrtf(fmaxf(best, 1e-12f));
}

// ---------------------------------------------------------------- 5. feat assembly
// writes A1' [16384][1632] bf16: sections hi | hi | lo of the 544-wide padded
// feature row [fa(256)|fb(256)|pa3|pb3|dist|score|pad24]
__global__ __launch_bounds__(256) void feat_assemble_kernel(
    const float* __restrict__ rf, const float* __restrict__ sf,
    const float* __restrict__ ptsn, const int* __restrict__ idx,
    const float* __restrict__ md, unsigned short* __restrict__ A1) {
    __shared__ float sm[256];
    int i = blockIdx.x, t = threadIdx.x;
    const float *fa, *fb, *pa, *pb; float dist;
    if (i < NREF) {
        int j = idx[i];
        fa = rf + (size_t)i * DF;  fb = sf + (size_t)j * DF;
        pa = ptsn + 3 * i;         pb = ptsn + 3 * (NREF + j);
        dist = md[i];
    } else {
        int jj = i - NREF;
        int j = idx[NREF + jj];
        fa = sf + (size_t)jj * DF; fb = rf + (size_t)j * DF;
        pa = ptsn + 3 * (NREF + jj); pb = ptsn + 3 * j;
        dist = md[NREF + jj];
    }
    float a = fa[t], b = fb[t];
    float sc = block_reduce_sum(a * b, sm);
    unsigned short* row = A1 + (size_t)i * K1X;
    unsigned short ah = f2bf_rn(a), al = f2bf_rn(a - bf2f(ah));
    unsigned short bh = f2bf_rn(b), bl = f2bf_rn(b - bf2f(bh));
    row[t] = ah;             row[K1P + t] = ah;             row[2 * K1P + t] = al;
    row[256 + t] = bh;       row[K1P + 256 + t] = bh;       row[2 * K1P + 256 + t] = bl;
    if (t < 8) {
        float v = (t < 3) ? pa[t] : (t < 6) ? pb[t - 3] : (t == 6) ? dist : sc;
        unsigned short vh = f2bf_rn(v), vl = f2bf_rn(v - bf2f(vh));
        row[512 + t] = vh;   row[K1P + 512 + t] = vh;       row[2 * K1P + 512 + t] = vl;
    }
    if (t < 24) {   // zero K-pad (B' pad rows are zero too; belt & braces)
        row[520 + t] = 0;    row[K1P + 520 + t] = 0;        row[2 * K1P + 520 + t] = 0;
    }
}

// ---------------------------------------------------------------- 6. bf16 GEMM
// C[M,N] = A'[M,K] @ B'T[N,K]^T + bias.  BM=64, BN=256, BK=32, 8 waves.
// LDS padded stride 40 ushorts (80B) to spread banks.
__global__ __launch_bounds__(512) void gemm_bf16_bt_kernel(
    const unsigned short* __restrict__ A, const unsigned short* __restrict__ B,
    const float* __restrict__ bias, float* __restrict__ C,
    int N, int K) {
    __shared__ unsigned short As[64][40];
    __shared__ unsigned short Bs[256][40];
    const int tid = threadIdx.x;
    const int row0 = blockIdx.x * 64, col0 = blockIdx.y * 256;
    const int lane = tid & 63, wid = tid >> 6;
    const int wr = wid >> 2, wc = wid & 3;          // 2x4 wave grid
    const int r = lane & 15, kg = lane >> 4;

    const int arow = tid >> 2, achk = tid & 3;      // A stage (tid<256)
    const int brow = tid >> 1, bhalf = tid & 1;     // B stage (all 512)

    f32x4 acc[2][4];
    #pragma unroll
    for (int i = 0; i < 2; ++i)
        #pragma unroll
        for (int j = 0; j < 4; ++j) acc[i][j] = (f32x4){0.f, 0.f, 0.f, 0.f};

    const int ns = K / 32;
    int4 aR = {0,0,0,0}, bR0, bR1;
    if (tid < 256) aR = *(const int4*)&A[(size_t)(row0 + arow) * K + achk * 8];
    bR0 = *(const int4*)&B[(size_t)(col0 + brow) * K + bhalf * 16];
    bR1 = *(const int4*)&B[(size_t)(col0 + brow) * K + bhalf * 16 + 8];

    for (int kt = 0; kt < ns; ++kt) {
        __syncthreads();
        if (tid < 256) *(int4*)&As[arow][achk * 8] = aR;
        *(int4*)&Bs[brow][bhalf * 16] = bR0;
        *(int4*)&Bs[brow][bhalf * 16 + 8] = bR1;
        __syncthreads();
        if (kt + 1 < ns) {
            int k0 = (kt + 1) * 32;
            if (tid < 256) aR = *(const int4*)&A[(size_t)(row0 + arow) * K + k0 + achk * 8];
            bR0 = *(const int4*)&B[(size_t)(col0 + brow) * K + k0 + bhalf * 16];
            bR1 = *(const int4*)&B[(size_t)(col0 + brow) * K + k0 + bhalf * 16 + 8];
        }
        bf16x8 af[2], bf[4];
        #pragma unroll
        for (int fi = 0; fi < 2; ++fi)
            af[fi] = *(const bf16x8*)&As[wr * 32 + fi * 16 + r][kg * 8];
        #pragma unroll
        for (int fj = 0; fj < 4; ++fj)
            bf[fj] = *(const bf16x8*)&Bs[wc * 64 + fj * 16 + r][kg * 8];
        #pragma unroll
        for (int fi = 0; fi < 2; ++fi)
            #pragma unroll
            for (int fj = 0; fj < 4; ++fj)
                acc[fi][fj] = __builtin_amdgcn_mfma_f32_16x16x32_bf16(
                    af[fi], bf[fj], acc[fi][fj], 0, 0, 0);
    }

    // C/D layout: col = lane&15, row = (lane>>4)*4 + reg   [m89-verified]
    #pragma unroll
    for (int fj = 0; fj < 4; ++fj) {
        int gcol = col0 + wc * 64 + fj * 16 + r;
        float bb = bias[gcol];
        #pragma unroll
        for (int fi = 0; fi < 2; ++fi) {
            int grow = row0 + wr * 32 + fi * 16 + kg * 4;
            #pragma unroll
            for (int i = 0; i < 4; ++i)
                C[(size_t)(grow + i) * N + gcol] = acc[fi][fj][i] + bb;
        }
    }
}

// ---------------------------------------------------------------- 7. instnorm+relu+split (h1 -> A2')
// wave per row: 4 rows/block, grid 4096
__global__ __launch_bounds__(256) void instnorm_split_kernel(
    const float* __restrict__ h1, unsigned short* __restrict__ A2) {
    int wid = threadIdx.x >> 6, lane = threadIdx.x & 63;
    int row = blockIdx.x * 4 + wid;
    float4 x = *(const float4*)&h1[(size_t)row * 256 + lane * 4];
    float s = x.x + x.y + x.z + x.w;
    float q = x.x * x.x + x.y * x.y + x.z * x.z + x.w * x.w;
    #pragma unroll
    for (int off = 32; off > 0; off >>= 1) {
        s += __shfl_xor(s, off, 64);
        q += __shfl_xor(q, off, 64);
    }
    float m = s * (1.0f / 256.0f);
    float var = q * (1.0f / 256.0f) - m * m;
    float rs = rsqrtf(var + EPSV);
    float y[4] = { fmaxf((x.x - m) * rs, 0.f), fmaxf((x.y - m) * rs, 0.f),
                   fmaxf((x.z - m) * rs, 0.f), fmaxf((x.w - m) * rs, 0.f) };
    ushort4 hi, lo;
    hi.x = f2bf_rn(y[0]); lo.x = f2bf_rn(y[0] - bf2f(hi.x));
    hi.y = f2bf_rn(y[1]); lo.y = f2bf_rn(y[1] - bf2f(hi.y));
    hi.z = f2bf_rn(y[2]); lo.z = f2bf_rn(y[2] - bf2f(hi.z));
    hi.w = f2bf_rn(y[3]); lo.w = f2bf_rn(y[3] - bf2f(hi.w));
    unsigned short* row_p = A2 + (size_t)row * K2X;
    *(ushort4*)&row_p[lane * 4] = hi;
    *(ushort4*)&row_p[256 + lane * 4] = hi;
    *(ushort4*)&row_p[512 + lane * 4] = lo;
}

// ---------------------------------------------------------------- 8. instnorm+relu+colsum (h2 -> mbar)
// 4 waves x 8 rows per block, grid 512; one atomicAdd per col per block.
__global__ __launch_bounds__(256) void instnorm_colsum_kernel(
    const float* __restrict__ h2, float* __restrict__ mbar) {
    __shared__ float cs[512];
    int t = threadIdx.x;
    int wid = t >> 6, lane = t & 63;
    float2 colacc[4] = {{0.f,0.f},{0.f,0.f},{0.f,0.f},{0.f,0.f}};
    #pragma unroll
    for (int rr = 0; rr < 8; ++rr) {
        int row = blockIdx.x * 32 + wid * 8 + rr;
        const float* rp = h2 + (size_t)row * 512;
        float2 xv[4];
        float s = 0.f, q = 0.f;
        #pragma unroll
        for (int j = 0; j < 4; ++j) {
            xv[j] = *(const float2*)&rp[j * 128 + lane * 2];
            s += xv[j].x + xv[j].y;
            q += xv[j].x * xv[j].x + xv[j].y * xv[j].y;
        }
        #pragma unroll
        for (int off = 32; off > 0; off >>= 1) {
            s += __shfl_xor(s, off, 64);
            q += __shfl_xor(q, off, 64);
        }
        float m = s * (1.0f / 512.0f);
        float var = q * (1.0f / 512.0f) - m * m;
        float rs = rsqrtf(var + EPSV);
        #pragma unroll
        for (int j = 0; j < 4; ++j) {
            colacc[j].x += fmaxf((xv[j].x - m) * rs, 0.f);
            colacc[j].y += fmaxf((xv[j].y - m) * rs, 0.f);
        }
    }
    cs[t] = 0.f; cs[t + 256] = 0.f;
    __syncthreads();
    for (int w = 0; w < 4; ++w) {
        if (wid == w) {
            #pragma unroll
            for (int j = 0; j < 4; ++j) {
                cs[j * 128 + lane * 2]     += colacc[j].x;
                cs[j * 128 + lane * 2 + 1] += colacc[j].y;
            }
        }
        __syncthreads();
    }
    atomicAdd(&mbar[t], cs[t]);
    atomicAdd(&mbar[t + 256], cs[t + 256]);
}

// ---------------------------------------------------------------- 9. pooled partial
// grid (4 colblk, 16 kblk): pool_raw[j] += (1/16384)*sum_k mbar[k]*W3[k][j]
__global__ __launch_bounds__(256) void pooled_mv_kernel(
    const float* __restrict__ mbar, const float* __restrict__ W3,
    float* __restrict__ pool_raw) {
    int j = blockIdx.x * 256 + threadIdx.x;
    int k0 = blockIdx.y * 32;
    float acc = 0.f;
    #pragma unroll 8
    for (int kk = 0; kk < 32; ++kk)
        acc = fmaf(mbar[k0 + kk], W3[(size_t)(k0 + kk) * 1024 + j], acc);
    atomicAdd(&pool_raw[j], acc * (1.0f / 16384.0f));
}

// ---------------------------------------------------------------- 10. c1 partial
// grid (2 colblk, 32 kblk): t1_raw[o] += sum_k (pool_raw[k]+b3[k])*Wc1[k][o]
__global__ __launch_bounds__(256) void c1_mv_kernel(
    const float* __restrict__ pool_raw, const float* __restrict__ b3,
    const float* __restrict__ Wc1, float* __restrict__ t1_raw) {
    int o = blockIdx.x * 256 + threadIdx.x;
    int k0 = blockIdx.y * 32;
    float acc = 0.f;
    #pragma unroll 8
    for (int kk = 0; kk < 32; ++kk)
        acc = fmaf(pool_raw[k0 + kk] + b3[k0 + kk],
                   Wc1[(size_t)(k0 + kk) * 512 + o], acc);
    atomicAdd(&t1_raw[o], acc);
}

// ---------------------------------------------------------------- 11. tail
__global__ __launch_bounds__(256) void tail_kernel(
    const float* __restrict__ t1_raw, const float* __restrict__ bc1,
    const float* __restrict__ g1, const float* __restrict__ be1,
    const float* __restrict__ Wc2, const float* __restrict__ bc2,
    const float* __restrict__ g2, const float* __restrict__ be2,
    const float* __restrict__ Wc3, const float* __restrict__ bc3,
    float* __restrict__ out) {
    __shared__ float a1[512];
    __shared__ float a2[256];
    __shared__ float gm[32], gv[32];
    int t = threadIdx.x;
    a1[t] = t1_raw[t] + bc1[t];
    a1[t + 256] = t1_raw[t + 256] + bc1[t + 256];
    __syncthreads();
    if (t < 32) {
        float s = 0.f;
        for (int k = 0; k < 16; ++k) s += a1[t * 16 + k];
        float m = s * (1.0f / 16.0f);
        float q = 0.f;
        for (int k = 0; k < 16; ++k) { float d = a1[t * 16 + k] - m; q += d * d; }
        gm[t] = m;
        gv[t] = rsqrtf(q * (1.0f / 16.0f) + EPSV);
    }
    __syncthreads();
    float v0 = (a1[t] - gm[t >> 4]) * gv[t >> 4];
    float v1 = (a1[t + 256] - gm[(t + 256) >> 4]) * gv[(t + 256) >> 4];
    v0 = fmaxf(fmaf(v0, g1[t], be1[t]), 0.f);
    v1 = fmaxf(fmaf(v1, g1[t + 256], be1[t + 256]), 0.f);
    __syncthreads();
    a1[t] = v0;
    a1[t + 256] = v1;
    __syncthreads();
    float acc = bc2[t];
    #pragma unroll 8
    for (int k = 0; k < 512; ++k) acc = fmaf(a1[k], Wc2[k * 256 + t], acc);
    a2[t] = acc;
    __syncthreads();
    if (t < 32) {
        float s = 0.f;
        for (int k = 0; k < 8; ++k) s += a2[t * 8 + k];
        float m = s * (1.0f / 8.0f);
        float q = 0.f;
        for (int k = 0; k < 8; ++k) { float d = a2[t * 8 + k] - m; q += d * d; }
        gm[t] = m;
        gv[t] = rsqrtf(q * (1.0f / 8.0f) + EPSV);
    }
    __syncthreads();
    float w = (a2[t] - gm[t >> 3]) * gv[t >> 3];
    w = fmaxf(fmaf(w, g2[t], be2[t]), 0.f);
    __syncthreads();
    a2[t] = w;
    __syncthreads();
    if (t < 2) {
        float acc2 = bc3[t];
        #pragma unroll 8
        for (int k = 0; k < 256; ++k) acc2 = fmaf(a2[k], Wc3[k * 2 + t], acc2);
        out[t] = acc2;
    }
}

// ============================================================================
extern "C" void kernel_launch(void* const* d_in, const int* in_sizes, int n_in,
                              void* d_out, int out_size, void* d_ws, size_t ws_size,
                              hipStream_t stream) {
    const float* ref_points = (const float*)d_in[0];
    const float* src_points = (const float*)d_in[1];
    const float* ref_feats  = (const float*)d_in[2];
    const float* src_feats  = (const float*)d_in[3];
    const float* W1  = (const float*)d_in[4];
    const float* b1  = (const float*)d_in[5];
    const float* W2  = (const float*)d_in[6];
    const float* b2  = (const float*)d_in[7];
    const float* W3  = (const float*)d_in[8];
    const float* b3  = (const float*)d_in[9];
    const float* Wc1 = (const float*)d_in[10];
    const float* bc1 = (const float*)d_in[11];
    const float* g1  = (const float*)d_in[12];
    const float* be1 = (const float*)d_in[13];
    const float* Wc2 = (const float*)d_in[14];
    const float* bc2 = (const float*)d_in[15];
    const float* g2  = (const float*)d_in[16];
    const float* be2 = (const float*)d_in[17];
    const float* Wc3 = (const float*)d_in[18];
    const float* bc3 = (const float*)d_in[19];
    float* out = (float*)d_out;

    float* ws = (float*)d_ws;
    float* rf   = ws + OFF_RF;
    float* sf   = ws + OFF_SF;
    float* ptsn = ws + OFF_PTSN;
    float* pmin = ws + OFF_PMIN;
    int*   pidx = (int*)(ws + OFF_PIDX);
    int*   idx  = (int*)(ws + OFF_IDX);
    float* md   = ws + OFF_MD;
    unsigned short* A1  = (unsigned short*)(ws + OFF_A1);
    unsigned short* A2  = (unsigned short*)(ws + OFF_A2);
    unsigned short* W1T = (unsigned short*)(ws + OFF_W1T);
    unsigned short* W2T = (unsigned short*)(ws + OFF_W2T);
    float* h1   = ws + OFF_H1;
    float* h2   = ws + OFF_H2;
    float* mbar     = ws + OFF_ZERO;
    float* pool_raw = ws + OFF_ZERO + 512;
    float* t1_raw   = ws + OFF_ZERO + 1536;

    hipMemsetAsync(mbar, 0, 2048 * sizeof(float), stream);

    hipLaunchKernelGGL(prep_w1_kernel, dim3(256), dim3(256), 0, stream, W1, W1T);
    hipLaunchKernelGGL(prep_w2_kernel, dim3(512), dim3(256), 0, stream, W2, W2T);
    hipLaunchKernelGGL(l2norm_kernel, dim3(NTOT), dim3(256), 0, stream,
                       ref_feats, src_feats, rf, sf);
    hipLaunchKernelGGL(pts_norm_kernel, dim3(1), dim3(256), 0, stream,
                       ref_points, src_points, ptsn);
    hipLaunchKernelGGL(dist_partial_kernel, dim3(32, 16, 2), dim3(256), 0, stream,
                       ref_points, src_points, pmin, pidx);
    hipLaunchKernelGGL(dist_reduce_kernel, dim3(64), dim3(256), 0, stream,
                       pmin, pidx, idx, md);
    hipLaunchKernelGGL(feat_assemble_kernel, dim3(NTOT), dim3(256), 0, stream,
                       rf, sf, ptsn, idx, md, A1);
    hipLaunchKernelGGL(gemm_bf16_bt_kernel, dim3(256, 1), dim3(512), 0, stream,
                       A1, W1T, b1, h1, 256, K1X);
    hipLaunchKernelGGL(instnorm_split_kernel, dim3(4096), dim3(256), 0, stream, h1, A2);
    hipLaunchKernelGGL(gemm_bf16_bt_kernel, dim3(256, 2), dim3(512), 0, stream,
                       A2, W2T, b2, h2, 512, K2X);
    hipLaunchKernelGGL(instnorm_colsum_kernel, dim3(512), dim3(256), 0, stream, h2, mbar);
    hipLaunchKernelGGL(pooled_mv_kernel, dim3(4, 16), dim3(256), 0, stream,
                       mbar, W3, pool_raw);
    hipLaunchKernelGGL(c1_mv_kernel, dim3(2, 32), dim3(256), 0, stream,
                       pool_raw, b3, Wc1, t1_raw);
    hipLaunchKernelGGL(tail_kernel, dim3(1), dim3(256), 0, stream,
                       t1_raw, bc1, g1, be1, Wc2, bc2, g2, be2, Wc3, bc3, out);
}

// Round 11
// 301.469 us; speedup vs baseline: 1.6110x; 1.1784x over previous
//
#include <hip/hip_runtime.h>
#include <math.h>

// ============================================================================
// GeoTransformer head — round 11: resubmit of rounds 4-10 (rounds 4-9 broker
// timeouts; round 10 container failure — both infra-side). Source frozen.
//
//  - pts_norm single-block (60us) replaced by 3 tiny reduction kernels
//    computing only {mean, R}; feat_assemble normalizes points inline.
//  - l2norm round-trip removed: only invnorms computed; feat_assemble scales.
//  - A' physical storage [hi|lo] (GEMM aliases logical sections hi,hi,lo),
//    saving 1/3 of A-matrix bytes both GEMMs.
//  - feat_assemble wave-per-row, ushort4 stores.
//
// ws layout (float units), total 17,758,720 fl = 67.75 MiB:
//  OFF_R = 0: A1(us,16384x1088)=[0,8912896) fl; dead after GEMM1, then
//             A2(us,16384x512)=[0,4194304) fl, h2(f32)=[4194304,12582912) fl
//  invn@12582912(16384) stats@12599296(512: mean3,R,psum192@+8,pmax64@+200)
//  pmin@12599808 pidx@12861952 idx@13124096 md@13140480
//  W1T@13156864 W2T@13365760 h1@13562368 zero@17756672(2048)
// ============================================================================

#define NREF 8192
#define NTOT 16384
#define DF   256
#define EPSV 1e-5f

#define SPLIT1 544
#define KA1    1088
#define K1X    1632
#define SPLIT2 256
#define KA2    512
#define K2X    768

#define OFF_R     0u
#define OFF_A2    0u
#define OFF_H2    4194304u
#define OFF_INVN  12582912u
#define OFF_STATS 12599296u
#define OFF_PMIN  12599808u
#define OFF_PIDX  12861952u
#define OFF_IDX   13124096u
#define OFF_MD    13140480u
#define OFF_W1T   13156864u
#define OFF_W2T   13365760u
#define OFF_H1    13562368u
#define OFF_ZERO  17756672u

typedef float f32x4 __attribute__((ext_vector_type(4)));
typedef __bf16 bf16x8 __attribute__((ext_vector_type(8)));

__device__ __forceinline__ unsigned short f2bf_rn(float x) {
    union { float f; unsigned int u; } v; v.f = x;
    unsigned int r = (v.u + 0x7FFFu + ((v.u >> 16) & 1u)) >> 16;
    return (unsigned short)r;
}
__device__ __forceinline__ float bf2f(unsigned short h) {
    union { unsigned int u; float f; } v; v.u = ((unsigned int)h) << 16;
    return v.f;
}

__device__ __forceinline__ float block_reduce_sum(float v, float* sm) {
    int t = threadIdx.x;
    sm[t] = v; __syncthreads();
    for (int s = 128; s > 0; s >>= 1) {
        if (t < s) sm[t] += sm[t + s];
        __syncthreads();
    }
    float r = sm[0]; __syncthreads();
    return r;
}
__device__ __forceinline__ float block_reduce_max(float v, float* sm) {
    int t = threadIdx.x;
    sm[t] = v; __syncthreads();
    for (int s = 128; s > 0; s >>= 1) {
        if (t < s) sm[t] = fmaxf(sm[t], sm[t + s]);
        __syncthreads();
    }
    float r = sm[0]; __syncthreads();
    return r;
}

// ---------------------------------------------------------------- weight prep
// B' layout (3K wide): sections [hi | lo | hi] pairing A logical [hi|hi|lo].
__global__ __launch_bounds__(256) void prep_w1_kernel(
    const float* __restrict__ W1, unsigned short* __restrict__ W1T) {
    int n = blockIdx.x;
    unsigned short* row = W1T + (size_t)n * K1X;
    for (int k = threadIdx.x; k < SPLIT1; k += 256) {
        unsigned short hi = 0, lo = 0;
        if (k < 520) {
            float x = W1[k * 256 + n];
            hi = f2bf_rn(x);
            lo = f2bf_rn(x - bf2f(hi));
        }
        row[k] = hi;
        row[SPLIT1 + k] = lo;
        row[2 * SPLIT1 + k] = hi;
    }
}

__global__ __launch_bounds__(256) void prep_w2_kernel(
    const float* __restrict__ W2, unsigned short* __restrict__ W2T) {
    int n = blockIdx.x;
    int k = threadIdx.x;
    float x = W2[k * 512 + n];
    unsigned short hi = f2bf_rn(x);
    unsigned short lo = f2bf_rn(x - bf2f(hi));
    unsigned short* row = W2T + (size_t)n * K2X;
    row[k] = hi;
    row[256 + k] = lo;
    row[512 + k] = hi;
}

// ---------------------------------------------------------------- feat invnorms
// wave per row, 4 rows/block, grid 4096
__global__ __launch_bounds__(256) void feat_norms_kernel(
    const float* __restrict__ rfeat, const float* __restrict__ sfeat,
    float* __restrict__ invn) {
    int wid = threadIdx.x >> 6, lane = threadIdx.x & 63;
    int row = blockIdx.x * 4 + wid;
    const float* in = (row < NREF) ? (rfeat + (size_t)row * DF)
                                   : (sfeat + (size_t)(row - NREF) * DF);
    float4 x = *(const float4*)&in[lane * 4];
    float q = x.x * x.x + x.y * x.y + x.z * x.z + x.w * x.w;
    #pragma unroll
    for (int off = 32; off > 0; off >>= 1) q += __shfl_xor(q, off, 64);
    if (lane == 0) invn[row] = 1.0f / fmaxf(sqrtf(q), 1e-12f);
}

// ---------------------------------------------------------------- pts stats
// k1: 64 blocks x 256 -> psum[blk][3]
__global__ __launch_bounds__(256) void pts_sum_kernel(
    const float* __restrict__ rp, const float* __restrict__ sp,
    float* __restrict__ psum) {
    __shared__ float sm[256];
    int i = blockIdx.x * 256 + threadIdx.x;
    const float* p = (i < NREF) ? (rp + 3 * i) : (sp + 3 * (i - NREF));
    float sx = block_reduce_sum(p[0], sm);
    float sy = block_reduce_sum(p[1], sm);
    float sz = block_reduce_sum(p[2], sm);
    if (threadIdx.x == 0) {
        psum[blockIdx.x * 3 + 0] = sx;
        psum[blockIdx.x * 3 + 1] = sy;
        psum[blockIdx.x * 3 + 2] = sz;
    }
}

// k2: 64 blocks x 256: mean from psum, partial max ||p-m||^2 -> pmax[blk]
__global__ __launch_bounds__(256) void pts_max_kernel(
    const float* __restrict__ rp, const float* __restrict__ sp,
    const float* __restrict__ psum, float* __restrict__ pmax) {
    __shared__ float sm[256];
    float mx = 0.f, my = 0.f, mz = 0.f;
    for (int k = 0; k < 64; ++k) {
        mx += psum[k * 3 + 0]; my += psum[k * 3 + 1]; mz += psum[k * 3 + 2];
    }
    mx *= (1.0f / NTOT); my *= (1.0f / NTOT); mz *= (1.0f / NTOT);
    int i = blockIdx.x * 256 + threadIdx.x;
    const float* p = (i < NREF) ? (rp + 3 * i) : (sp + 3 * (i - NREF));
    float dx = p[0] - mx, dy = p[1] - my, dz = p[2] - mz;
    float v = block_reduce_max(dx * dx + dy * dy + dz * dz, sm);
    if (threadIdx.x == 0) pmax[blockIdx.x] = v;
}

// k3: 1 block x 64: stats[0..2]=mean, stats[3]=R
__global__ __launch_bounds__(64) void pts_final_kernel(
    const float* __restrict__ psum, const float* __restrict__ pmax,
    float* __restrict__ stats) {
    int lane = threadIdx.x;
    float v = pmax[lane];
    #pragma unroll
    for (int off = 32; off > 0; off >>= 1) v = fmaxf(v, __shfl_xor(v, off, 64));
    if (lane == 0) {
        float mx = 0.f, my = 0.f, mz = 0.f;
        for (int k = 0; k < 64; ++k) {
            mx += psum[k * 3 + 0]; my += psum[k * 3 + 1]; mz += psum[k * 3 + 2];
        }
        stats[0] = mx * (1.0f / NTOT);
        stats[1] = my * (1.0f / NTOT);
        stats[2] = mz * (1.0f / NTOT);
        stats[3] = sqrtf(v);
    }
}

// ---------------------------------------------------------------- NN partial
__global__ __launch_bounds__(256) void dist_partial_kernel(
    const float* __restrict__ rp, const float* __restrict__ sp,
    float* __restrict__ pmin, int* __restrict__ pidx) {
    __shared__ float4 tg[512];
    int pass = blockIdx.z;
    const float* Q = pass ? sp : rp;
    const float* T = pass ? rp : sp;
    int t = threadIdx.x;
    int j0 = blockIdx.y * 512;
    for (int k = t; k < 512; k += 256) {
        float x = T[3 * (j0 + k) + 0];
        float y = T[3 * (j0 + k) + 1];
        float z = T[3 * (j0 + k) + 2];
        tg[k] = make_float4(x, y, z, x * x + y * y + z * z);
    }
    __syncthreads();
    int qid = blockIdx.x * 256 + t;
    float qx = Q[3 * qid + 0], qy = Q[3 * qid + 1], qz = Q[3 * qid + 2];
    float rr = qx * qx + qy * qy + qz * qz;
    float best = 3.4e38f; int bj = 0;
    #pragma unroll 4
    for (int j = 0; j < 512; ++j) {
        float4 f = tg[j];
        float dot = qx * f.x + qy * f.y + qz * f.z;
        float d2 = rr + f.w - 2.0f * dot;
        if (d2 < best) { best = d2; bj = j; }
    }
    int slot = ((pass << 4) + blockIdx.y) * 8192 + qid;
    pmin[slot] = best;
    pidx[slot] = j0 + bj;
}

// ---------------------------------------------------------------- NN reduce
__global__ __launch_bounds__(256) void dist_reduce_kernel(
    const float* __restrict__ pmin, const int* __restrict__ pidx,
    int* __restrict__ idx, float* __restrict__ md) {
    int gid = blockIdx.x * 256 + threadIdx.x;
    int pass = gid >> 13;
    int q = gid & 8191;
    float best = 3.4e38f; int bi = 0;
    #pragma unroll
    for (int s = 0; s < 16; ++s) {
        int slot = ((pass << 4) + s) * 8192 + q;
        float v = pmin[slot];
        if (v < best) { best = v; bi = pidx[slot]; }
    }
    idx[pass * 8192 + q] = bi;
    md[pass * 8192 + q] = sqrtf(fmaxf(best, 1e-12f));
}

// ---------------------------------------------------------------- feat assembly
// wave per row, 4 rows/block, grid 4096. A1 row = [hi(544) | lo(544)],
// cols: fa 0..255, fb 256..511, pa 512..514, pb 515..517, dist 518, score 519,
// pad 520..543 zero.
__global__ __launch_bounds__(256) void feat_assemble_kernel(
    const float* __restrict__ rfeat, const float* __restrict__ sfeat,
    const float* __restrict__ rp, const float* __restrict__ sp,
    const float* __restrict__ invn, const float* __restrict__ stats,
    const int* __restrict__ idx, const float* __restrict__ md,
    unsigned short* __restrict__ A1) {
    int wid = threadIdx.x >> 6, lane = threadIdx.x & 63;
    int i = blockIdx.x * 4 + wid;
    float mx = stats[0], my = stats[1], mz = stats[2], rinv = 1.0f / stats[3];

    const float *fa, *fb, *pA, *pB;
    float inva, invb, dist;
    if (i < NREF) {
        int j = idx[i];
        fa = rfeat + (size_t)i * DF;  fb = sfeat + (size_t)j * DF;
        inva = invn[i];               invb = invn[NREF + j];
        pA = rp + 3 * i;              pB = sp + 3 * j;
        dist = md[i];
    } else {
        int jj = i - NREF;
        int j = idx[NREF + jj];
        fa = sfeat + (size_t)jj * DF; fb = rfeat + (size_t)j * DF;
        inva = invn[NREF + jj];       invb = invn[j];
        pA = sp + 3 * jj;             pB = rp + 3 * j;
        dist = md[NREF + jj];
    }

    float4 a4 = *(const float4*)&fa[lane * 4];
    float4 b4 = *(const float4*)&fb[lane * 4];
    a4.x *= inva; a4.y *= inva; a4.z *= inva; a4.w *= inva;
    b4.x *= invb; b4.y *= invb; b4.z *= invb; b4.w *= invb;
    float d = a4.x * b4.x + a4.y * b4.y + a4.z * b4.z + a4.w * b4.w;
    #pragma unroll
    for (int off = 32; off > 0; off >>= 1) d += __shfl_xor(d, off, 64);

    unsigned short* row = A1 + (size_t)i * KA1;
    ushort4 h, l;
    h.x = f2bf_rn(a4.x); l.x = f2bf_rn(a4.x - bf2f(h.x));
    h.y = f2bf_rn(a4.y); l.y = f2bf_rn(a4.y - bf2f(h.y));
    h.z = f2bf_rn(a4.z); l.z = f2bf_rn(a4.z - bf2f(h.z));
    h.w = f2bf_rn(a4.w); l.w = f2bf_rn(a4.w - bf2f(h.w));
    *(ushort4*)&row[lane * 4] = h;
    *(ushort4*)&row[SPLIT1 + lane * 4] = l;
    h.x = f2bf_rn(b4.x); l.x = f2bf_rn(b4.x - bf2f(h.x));
    h.y = f2bf_rn(b4.y); l.y = f2bf_rn(b4.y - bf2f(h.y));
    h.z = f2bf_rn(b4.z); l.z = f2bf_rn(b4.z - bf2f(h.z));
    h.w = f2bf_rn(b4.w); l.w = f2bf_rn(b4.w - bf2f(h.w));
    *(ushort4*)&row[256 + lane * 4] = h;
    *(ushort4*)&row[SPLIT1 + 256 + lane * 4] = l;

    if (lane < 8) {
        float v;
        if (lane < 3)      v = (&pA[0])[lane];
        else if (lane < 6) v = (&pB[0])[lane - 3];
        else if (lane == 6) v = dist;
        else               v = d;
        if (lane < 3)      v = (v - ((lane == 0) ? mx : (lane == 1) ? my : mz)) * rinv;
        else if (lane < 6) v = (v - ((lane == 3) ? mx : (lane == 4) ? my : mz)) * rinv;
        unsigned short vh = f2bf_rn(v), vl = f2bf_rn(v - bf2f(vh));
        row[512 + lane] = vh;
        row[SPLIT1 + 512 + lane] = vl;
    } else if (lane < 32) {
        row[512 + lane] = 0;
        row[SPLIT1 + 512 + lane] = 0;
    }
}

// ---------------------------------------------------------------- bf16 GEMM
// C = A' @ B'T^T + bias. Logical K (3*SPLIT); A physical [hi|lo] width KA=2*SPLIT:
// kphys = k < SPLIT ? k : k - SPLIT  (aliases logical hi,hi,lo).
__global__ __launch_bounds__(512) void gemm_bf16_bt_kernel(
    const unsigned short* __restrict__ A, const unsigned short* __restrict__ B,
    const float* __restrict__ bias, float* __restrict__ C,
    int N, int K, int KA, int SPLIT) {
    __shared__ unsigned short As[64][40];
    __shared__ unsigned short Bs[256][40];
    const int tid = threadIdx.x;
    const int row0 = blockIdx.x * 64, col0 = blockIdx.y * 256;
    const int lane = tid & 63, wid = tid >> 6;
    const int wr = wid >> 2, wc = wid & 3;
    const int r = lane & 15, kg = lane >> 4;

    const int arow = tid >> 2, achk = tid & 3;
    const int brow = tid >> 1, bhalf = tid & 1;

    f32x4 acc[2][4];
    #pragma unroll
    for (int i = 0; i < 2; ++i)
        #pragma unroll
        for (int j = 0; j < 4; ++j) acc[i][j] = (f32x4){0.f, 0.f, 0.f, 0.f};

    const int ns = K / 32;
    int4 aR = {0, 0, 0, 0}, bR0, bR1;
    if (tid < 256) aR = *(const int4*)&A[(size_t)(row0 + arow) * KA + achk * 8];
    bR0 = *(const int4*)&B[(size_t)(col0 + brow) * K + bhalf * 16];
    bR1 = *(const int4*)&B[(size_t)(col0 + brow) * K + bhalf * 16 + 8];

    for (int kt = 0; kt < ns; ++kt) {
        __syncthreads();
        if (tid < 256) *(int4*)&As[arow][achk * 8] = aR;
        *(int4*)&Bs[brow][bhalf * 16] = bR0;
        *(int4*)&Bs[brow][bhalf * 16 + 8] = bR1;
        __syncthreads();
        if (kt + 1 < ns) {
            int k0 = (kt + 1) * 32;
            int kp = (k0 < SPLIT) ? k0 : k0 - SPLIT;
            if (tid < 256) aR = *(const int4*)&A[(size_t)(row0 + arow) * KA + kp + achk * 8];
            bR0 = *(const int4*)&B[(size_t)(col0 + brow) * K + k0 + bhalf * 16];
            bR1 = *(const int4*)&B[(size_t)(col0 + brow) * K + k0 + bhalf * 16 + 8];
        }
        bf16x8 af[2], bf[4];
        #pragma unroll
        for (int fi = 0; fi < 2; ++fi)
            af[fi] = *(const bf16x8*)&As[wr * 32 + fi * 16 + r][kg * 8];
        #pragma unroll
        for (int fj = 0; fj < 4; ++fj)
            bf[fj] = *(const bf16x8*)&Bs[wc * 64 + fj * 16 + r][kg * 8];
        #pragma unroll
        for (int fi = 0; fi < 2; ++fi)
            #pragma unroll
            for (int fj = 0; fj < 4; ++fj)
                acc[fi][fj] = __builtin_amdgcn_mfma_f32_16x16x32_bf16(
                    af[fi], bf[fj], acc[fi][fj], 0, 0, 0);
    }

    #pragma unroll
    for (int fj = 0; fj < 4; ++fj) {
        int gcol = col0 + wc * 64 + fj * 16 + r;
        float bb = bias[gcol];
        #pragma unroll
        for (int fi = 0; fi < 2; ++fi) {
            int grow = row0 + wr * 32 + fi * 16 + kg * 4;
            #pragma unroll
            for (int i = 0; i < 4; ++i)
                C[(size_t)(grow + i) * N + gcol] = acc[fi][fj][i] + bb;
        }
    }
}

// ---------------------------------------------------------------- instnorm+relu+split (h1 -> A2')
__global__ __launch_bounds__(256) void instnorm_split_kernel(
    const float* __restrict__ h1, unsigned short* __restrict__ A2) {
    int wid = threadIdx.x >> 6, lane = threadIdx.x & 63;
    int row = blockIdx.x * 4 + wid;
    float4 x = *(const float4*)&h1[(size_t)row * 256 + lane * 4];
    float s = x.x + x.y + x.z + x.w;
    float q = x.x * x.x + x.y * x.y + x.z * x.z + x.w * x.w;
    #pragma unroll
    for (int off = 32; off > 0; off >>= 1) {
        s += __shfl_xor(s, off, 64);
        q += __shfl_xor(q, off, 64);
    }
    float m = s * (1.0f / 256.0f);
    float var = q * (1.0f / 256.0f) - m * m;
    float rs = rsqrtf(var + EPSV);
    float y[4] = { fmaxf((x.x - m) * rs, 0.f), fmaxf((x.y - m) * rs, 0.f),
                   fmaxf((x.z - m) * rs, 0.f), fmaxf((x.w - m) * rs, 0.f) };
    ushort4 hi, lo;
    hi.x = f2bf_rn(y[0]); lo.x = f2bf_rn(y[0] - bf2f(hi.x));
    hi.y = f2bf_rn(y[1]); lo.y = f2bf_rn(y[1] - bf2f(hi.y));
    hi.z = f2bf_rn(y[2]); lo.z = f2bf_rn(y[2] - bf2f(hi.z));
    hi.w = f2bf_rn(y[3]); lo.w = f2bf_rn(y[3] - bf2f(hi.w));
    unsigned short* row_p = A2 + (size_t)row * KA2;
    *(ushort4*)&row_p[lane * 4] = hi;
    *(ushort4*)&row_p[SPLIT2 + lane * 4] = lo;
}

// ---------------------------------------------------------------- instnorm+relu+colsum
__global__ __launch_bounds__(256) void instnorm_colsum_kernel(
    const float* __restrict__ h2, float* __restrict__ mbar) {
    __shared__ float cs[512];
    int t = threadIdx.x;
    int wid = t >> 6, lane = t & 63;
    float2 colacc[4] = {{0.f,0.f},{0.f,0.f},{0.f,0.f},{0.f,0.f}};
    #pragma unroll
    for (int rr = 0; rr < 8; ++rr) {
        int row = blockIdx.x * 32 + wid * 8 + rr;
        const float* rp = h2 + (size_t)row * 512;
        float2 xv[4];
        float s = 0.f, q = 0.f;
        #pragma unroll
        for (int j = 0; j < 4; ++j) {
            xv[j] = *(const float2*)&rp[j * 128 + lane * 2];
            s += xv[j].x + xv[j].y;
            q += xv[j].x * xv[j].x + xv[j].y * xv[j].y;
        }
        #pragma unroll
        for (int off = 32; off > 0; off >>= 1) {
            s += __shfl_xor(s, off, 64);
            q += __shfl_xor(q, off, 64);
        }
        float m = s * (1.0f / 512.0f);
        float var = q * (1.0f / 512.0f) - m * m;
        float rs = rsqrtf(var + EPSV);
        #pragma unroll
        for (int j = 0; j < 4; ++j) {
            colacc[j].x += fmaxf((xv[j].x - m) * rs, 0.f);
            colacc[j].y += fmaxf((xv[j].y - m) * rs, 0.f);
        }
    }
    cs[t] = 0.f; cs[t + 256] = 0.f;
    __syncthreads();
    for (int w = 0; w < 4; ++w) {
        if (wid == w) {
            #pragma unroll
            for (int j = 0; j < 4; ++j) {
                cs[j * 128 + lane * 2]     += colacc[j].x;
                cs[j * 128 + lane * 2 + 1] += colacc[j].y;
            }
        }
        __syncthreads();
    }
    atomicAdd(&mbar[t], cs[t]);
    atomicAdd(&mbar[t + 256], cs[t + 256]);
}

// ---------------------------------------------------------------- pooled partial
__global__ __launch_bounds__(256) void pooled_mv_kernel(
    const float* __restrict__ mbar, const float* __restrict__ W3,
    float* __restrict__ pool_raw) {
    int j = blockIdx.x * 256 + threadIdx.x;
    int k0 = blockIdx.y * 32;
    float acc = 0.f;
    #pragma unroll 8
    for (int kk = 0; kk < 32; ++kk)
        acc = fmaf(mbar[k0 + kk], W3[(size_t)(k0 + kk) * 1024 + j], acc);
    atomicAdd(&pool_raw[j], acc * (1.0f / 16384.0f));
}

// ---------------------------------------------------------------- c1 partial
__global__ __launch_bounds__(256) void c1_mv_kernel(
    const float* __restrict__ pool_raw, const float* __restrict__ b3,
    const float* __restrict__ Wc1, float* __restrict__ t1_raw) {
    int o = blockIdx.x * 256 + threadIdx.x;
    int k0 = blockIdx.y * 32;
    float acc = 0.f;
    #pragma unroll 8
    for (int kk = 0; kk < 32; ++kk)
        acc = fmaf(pool_raw[k0 + kk] + b3[k0 + kk],
                   Wc1[(size_t)(k0 + kk) * 512 + o], acc);
    atomicAdd(&t1_raw[o], acc);
}

// ---------------------------------------------------------------- tail
__global__ __launch_bounds__(256) void tail_kernel(
    const float* __restrict__ t1_raw, const float* __restrict__ bc1,
    const float* __restrict__ g1, const float* __restrict__ be1,
    const float* __restrict__ Wc2, const float* __restrict__ bc2,
    const float* __restrict__ g2, const float* __restrict__ be2,
    const float* __restrict__ Wc3, const float* __restrict__ bc3,
    float* __restrict__ out) {
    __shared__ float a1[512];
    __shared__ float a2[256];
    __shared__ float gm[32], gv[32];
    int t = threadIdx.x;
    a1[t] = t1_raw[t] + bc1[t];
    a1[t + 256] = t1_raw[t + 256] + bc1[t + 256];
    __syncthreads();
    if (t < 32) {
        float s = 0.f;
        for (int k = 0; k < 16; ++k) s += a1[t * 16 + k];
        float m = s * (1.0f / 16.0f);
        float q = 0.f;
        for (int k = 0; k < 16; ++k) { float d = a1[t * 16 + k] - m; q += d * d; }
        gm[t] = m;
        gv[t] = rsqrtf(q * (1.0f / 16.0f) + EPSV);
    }
    __syncthreads();
    float v0 = (a1[t] - gm[t >> 4]) * gv[t >> 4];
    float v1 = (a1[t + 256] - gm[(t + 256) >> 4]) * gv[(t + 256) >> 4];
    v0 = fmaxf(fmaf(v0, g1[t], be1[t]), 0.f);
    v1 = fmaxf(fmaf(v1, g1[t + 256], be1[t + 256]), 0.f);
    __syncthreads();
    a1[t] = v0;
    a1[t + 256] = v1;
    __syncthreads();
    float acc = bc2[t];
    #pragma unroll 8
    for (int k = 0; k < 512; ++k) acc = fmaf(a1[k], Wc2[k * 256 + t], acc);
    a2[t] = acc;
    __syncthreads();
    if (t < 32) {
        float s = 0.f;
        for (int k = 0; k < 8; ++k) s += a2[t * 8 + k];
        float m = s * (1.0f / 8.0f);
        float q = 0.f;
        for (int k = 0; k < 8; ++k) { float d = a2[t * 8 + k] - m; q += d * d; }
        gm[t] = m;
        gv[t] = rsqrtf(q * (1.0f / 8.0f) + EPSV);
    }
    __syncthreads();
    float w = (a2[t] - gm[t >> 3]) * gv[t >> 3];
    w = fmaxf(fmaf(w, g2[t], be2[t]), 0.f);
    __syncthreads();
    a2[t] = w;
    __syncthreads();
    if (t < 2) {
        float acc2 = bc3[t];
        #pragma unroll 8
        for (int k = 0; k < 256; ++k) acc2 = fmaf(a2[k], Wc3[k * 2 + t], acc2);
        out[t] = acc2;
    }
}

// ============================================================================
extern "C" void kernel_launch(void* const* d_in, const int* in_sizes, int n_in,
                              void* d_out, int out_size, void* d_ws, size_t ws_size,
                              hipStream_t stream) {
    const float* ref_points = (const float*)d_in[0];
    const float* src_points = (const float*)d_in[1];
    const float* ref_feats  = (const float*)d_in[2];
    const float* src_feats  = (const float*)d_in[3];
    const float* W1  = (const float*)d_in[4];
    const float* b1  = (const float*)d_in[5];
    const float* W2  = (const float*)d_in[6];
    const float* b2  = (const float*)d_in[7];
    const float* W3  = (const float*)d_in[8];
    const float* b3  = (const float*)d_in[9];
    const float* Wc1 = (const float*)d_in[10];
    const float* bc1 = (const float*)d_in[11];
    const float* g1  = (const float*)d_in[12];
    const float* be1 = (const float*)d_in[13];
    const float* Wc2 = (const float*)d_in[14];
    const float* bc2 = (const float*)d_in[15];
    const float* g2  = (const float*)d_in[16];
    const float* be2 = (const float*)d_in[17];
    const float* Wc3 = (const float*)d_in[18];
    const float* bc3 = (const float*)d_in[19];
    float* out = (float*)d_out;

    float* ws = (float*)d_ws;
    unsigned short* A1  = (unsigned short*)(ws + OFF_R);
    unsigned short* A2  = (unsigned short*)(ws + OFF_A2);
    float* h2   = ws + OFF_H2;
    float* invn = ws + OFF_INVN;
    float* stats = ws + OFF_STATS;
    float* psum = stats + 8;
    float* pmax = stats + 200;
    float* pmin = ws + OFF_PMIN;
    int*   pidx = (int*)(ws + OFF_PIDX);
    int*   idx  = (int*)(ws + OFF_IDX);
    float* md   = ws + OFF_MD;
    unsigned short* W1T = (unsigned short*)(ws + OFF_W1T);
    unsigned short* W2T = (unsigned short*)(ws + OFF_W2T);
    float* h1   = ws + OFF_H1;
    float* mbar     = ws + OFF_ZERO;
    float* pool_raw = ws + OFF_ZERO + 512;
    float* t1_raw   = ws + OFF_ZERO + 1536;

    hipMemsetAsync(mbar, 0, 2048 * sizeof(float), stream);

    hipLaunchKernelGGL(prep_w1_kernel, dim3(256), dim3(256), 0, stream, W1, W1T);
    hipLaunchKernelGGL(prep_w2_kernel, dim3(512), dim3(256), 0, stream, W2, W2T);
    hipLaunchKernelGGL(feat_norms_kernel, dim3(4096), dim3(256), 0, stream,
                       ref_feats, src_feats, invn);
    hipLaunchKernelGGL(pts_sum_kernel, dim3(64), dim3(256), 0, stream,
                       ref_points, src_points, psum);
    hipLaunchKernelGGL(pts_max_kernel, dim3(64), dim3(256), 0, stream,
                       ref_points, src_points, psum, pmax);
    hipLaunchKernelGGL(pts_final_kernel, dim3(1), dim3(64), 0, stream,
                       psum, pmax, stats);
    hipLaunchKernelGGL(dist_partial_kernel, dim3(32, 16, 2), dim3(256), 0, stream,
                       ref_points, src_points, pmin, pidx);
    hipLaunchKernelGGL(dist_reduce_kernel, dim3(64), dim3(256), 0, stream,
                       pmin, pidx, idx, md);
    hipLaunchKernelGGL(feat_assemble_kernel, dim3(4096), dim3(256), 0, stream,
                       ref_feats, src_feats, ref_points, src_points,
                       invn, stats, idx, md, A1);
    hipLaunchKernelGGL(gemm_bf16_bt_kernel, dim3(256, 1), dim3(512), 0, stream,
                       A1, W1T, b1, h1, 256, K1X, KA1, SPLIT1);
    hipLaunchKernelGGL(instnorm_split_kernel, dim3(4096), dim3(256), 0, stream, h1, A2);
    hipLaunchKernelGGL(gemm_bf16_bt_kernel, dim3(256, 2), dim3(512), 0, stream,
                       A2, W2T, b2, h2, 512, K2X, KA2, SPLIT2);
    hipLaunchKernelGGL(instnorm_colsum_kernel, dim3(512), dim3(256), 0, stream, h2, mbar);
    hipLaunchKernelGGL(pooled_mv_kernel, dim3(4, 16), dim3(256), 0, stream,
                       mbar, W3, pool_raw);
    hipLaunchKernelGGL(c1_mv_kernel, dim3(2, 32), dim3(256), 0, stream,
                       pool_raw, b3, Wc1, t1_raw);
    hipLaunchKernelGGL(tail_kernel, dim3(1), dim3(256), 0, stream,
                       t1_raw, bc1, g1, be1, Wc2, bc2, g2, be2, Wc3, bc3, out);
}

// Round 12
// 287.867 us; speedup vs baseline: 1.6871x; 1.0473x over previous
//
#include <hip/hip_runtime.h>
#include <math.h>

// ============================================================================
// GeoTransformer head — round 12: dist_partial v2 (the measured 48us #1).
//  - 2 queries/thread: one LDS read feeds 2 min-chains (LDS/eval halved, ILP x2)
//  - rr dropped from comparison (constant per query); dist_reduce re-adds it.
//  - grid (16,16,2). Everything else frozen from the 301us round-11 kernel.
//
// ws layout (float units), total 17,758,720 fl = 67.75 MiB:
//  OFF_R = 0: A1(us,16384x1088)=[0,8912896) fl; dead after GEMM1, then
//             A2(us,16384x512)=[0,4194304) fl, h2(f32)=[4194304,12582912) fl
//  invn@12582912(16384) stats@12599296(512: mean3,R,psum192@+8,pmax64@+200)
//  pmin@12599808 pidx@12861952 idx@13124096 md@13140480
//  W1T@13156864 W2T@13365760 h1@13562368 zero@17756672(2048)
// ============================================================================

#define NREF 8192
#define NTOT 16384
#define DF   256
#define EPSV 1e-5f

#define SPLIT1 544
#define KA1    1088
#define K1X    1632
#define SPLIT2 256
#define KA2    512
#define K2X    768

#define OFF_R     0u
#define OFF_A2    0u
#define OFF_H2    4194304u
#define OFF_INVN  12582912u
#define OFF_STATS 12599296u
#define OFF_PMIN  12599808u
#define OFF_PIDX  12861952u
#define OFF_IDX   13124096u
#define OFF_MD    13140480u
#define OFF_W1T   13156864u
#define OFF_W2T   13365760u
#define OFF_H1    13562368u
#define OFF_ZERO  17756672u

typedef float f32x4 __attribute__((ext_vector_type(4)));
typedef __bf16 bf16x8 __attribute__((ext_vector_type(8)));

__device__ __forceinline__ unsigned short f2bf_rn(float x) {
    union { float f; unsigned int u; } v; v.f = x;
    unsigned int r = (v.u + 0x7FFFu + ((v.u >> 16) & 1u)) >> 16;
    return (unsigned short)r;
}
__device__ __forceinline__ float bf2f(unsigned short h) {
    union { unsigned int u; float f; } v; v.u = ((unsigned int)h) << 16;
    return v.f;
}

__device__ __forceinline__ float block_reduce_sum(float v, float* sm) {
    int t = threadIdx.x;
    sm[t] = v; __syncthreads();
    for (int s = 128; s > 0; s >>= 1) {
        if (t < s) sm[t] += sm[t + s];
        __syncthreads();
    }
    float r = sm[0]; __syncthreads();
    return r;
}
__device__ __forceinline__ float block_reduce_max(float v, float* sm) {
    int t = threadIdx.x;
    sm[t] = v; __syncthreads();
    for (int s = 128; s > 0; s >>= 1) {
        if (t < s) sm[t] = fmaxf(sm[t], sm[t + s]);
        __syncthreads();
    }
    float r = sm[0]; __syncthreads();
    return r;
}

// ---------------------------------------------------------------- weight prep
// B' layout (3K wide): sections [hi | lo | hi] pairing A logical [hi|hi|lo].
__global__ __launch_bounds__(256) void prep_w1_kernel(
    const float* __restrict__ W1, unsigned short* __restrict__ W1T) {
    int n = blockIdx.x;
    unsigned short* row = W1T + (size_t)n * K1X;
    for (int k = threadIdx.x; k < SPLIT1; k += 256) {
        unsigned short hi = 0, lo = 0;
        if (k < 520) {
            float x = W1[k * 256 + n];
            hi = f2bf_rn(x);
            lo = f2bf_rn(x - bf2f(hi));
        }
        row[k] = hi;
        row[SPLIT1 + k] = lo;
        row[2 * SPLIT1 + k] = hi;
    }
}

__global__ __launch_bounds__(256) void prep_w2_kernel(
    const float* __restrict__ W2, unsigned short* __restrict__ W2T) {
    int n = blockIdx.x;
    int k = threadIdx.x;
    float x = W2[k * 512 + n];
    unsigned short hi = f2bf_rn(x);
    unsigned short lo = f2bf_rn(x - bf2f(hi));
    unsigned short* row = W2T + (size_t)n * K2X;
    row[k] = hi;
    row[256 + k] = lo;
    row[512 + k] = hi;
}

// ---------------------------------------------------------------- feat invnorms
// wave per row, 4 rows/block, grid 4096
__global__ __launch_bounds__(256) void feat_norms_kernel(
    const float* __restrict__ rfeat, const float* __restrict__ sfeat,
    float* __restrict__ invn) {
    int wid = threadIdx.x >> 6, lane = threadIdx.x & 63;
    int row = blockIdx.x * 4 + wid;
    const float* in = (row < NREF) ? (rfeat + (size_t)row * DF)
                                   : (sfeat + (size_t)(row - NREF) * DF);
    float4 x = *(const float4*)&in[lane * 4];
    float q = x.x * x.x + x.y * x.y + x.z * x.z + x.w * x.w;
    #pragma unroll
    for (int off = 32; off > 0; off >>= 1) q += __shfl_xor(q, off, 64);
    if (lane == 0) invn[row] = 1.0f / fmaxf(sqrtf(q), 1e-12f);
}

// ---------------------------------------------------------------- pts stats
// k1: 64 blocks x 256 -> psum[blk][3]
__global__ __launch_bounds__(256) void pts_sum_kernel(
    const float* __restrict__ rp, const float* __restrict__ sp,
    float* __restrict__ psum) {
    __shared__ float sm[256];
    int i = blockIdx.x * 256 + threadIdx.x;
    const float* p = (i < NREF) ? (rp + 3 * i) : (sp + 3 * (i - NREF));
    float sx = block_reduce_sum(p[0], sm);
    float sy = block_reduce_sum(p[1], sm);
    float sz = block_reduce_sum(p[2], sm);
    if (threadIdx.x == 0) {
        psum[blockIdx.x * 3 + 0] = sx;
        psum[blockIdx.x * 3 + 1] = sy;
        psum[blockIdx.x * 3 + 2] = sz;
    }
}

// k2: 64 blocks x 256: mean from psum, partial max ||p-m||^2 -> pmax[blk]
__global__ __launch_bounds__(256) void pts_max_kernel(
    const float* __restrict__ rp, const float* __restrict__ sp,
    const float* __restrict__ psum, float* __restrict__ pmax) {
    __shared__ float sm[256];
    float mx = 0.f, my = 0.f, mz = 0.f;
    for (int k = 0; k < 64; ++k) {
        mx += psum[k * 3 + 0]; my += psum[k * 3 + 1]; mz += psum[k * 3 + 2];
    }
    mx *= (1.0f / NTOT); my *= (1.0f / NTOT); mz *= (1.0f / NTOT);
    int i = blockIdx.x * 256 + threadIdx.x;
    const float* p = (i < NREF) ? (rp + 3 * i) : (sp + 3 * (i - NREF));
    float dx = p[0] - mx, dy = p[1] - my, dz = p[2] - mz;
    float v = block_reduce_max(dx * dx + dy * dy + dz * dz, sm);
    if (threadIdx.x == 0) pmax[blockIdx.x] = v;
}

// k3: 1 block x 64: stats[0..2]=mean, stats[3]=R
__global__ __launch_bounds__(64) void pts_final_kernel(
    const float* __restrict__ psum, const float* __restrict__ pmax,
    float* __restrict__ stats) {
    int lane = threadIdx.x;
    float v = pmax[lane];
    #pragma unroll
    for (int off = 32; off > 0; off >>= 1) v = fmaxf(v, __shfl_xor(v, off, 64));
    if (lane == 0) {
        float mx = 0.f, my = 0.f, mz = 0.f;
        for (int k = 0; k < 64; ++k) {
            mx += psum[k * 3 + 0]; my += psum[k * 3 + 1]; mz += psum[k * 3 + 2];
        }
        stats[0] = mx * (1.0f / NTOT);
        stats[1] = my * (1.0f / NTOT);
        stats[2] = mz * (1.0f / NTOT);
        stats[3] = sqrtf(v);
    }
}

// ---------------------------------------------------------------- NN partial v2
// grid (16, 16, 2), block 256: 512 queries (2/thread) x 512-target slice.
// Comparison value EXCLUDES rr (constant per query): argmin unchanged;
// dist_reduce re-adds rr. One LDS read feeds both query chains.
__global__ __launch_bounds__(256) void dist_partial_kernel(
    const float* __restrict__ rp, const float* __restrict__ sp,
    float* __restrict__ pmin, int* __restrict__ pidx) {
    __shared__ float4 tg[512];
    int pass = blockIdx.z;
    const float* Q = pass ? sp : rp;
    const float* T = pass ? rp : sp;
    int t = threadIdx.x;
    int j0 = blockIdx.y * 512;
    for (int k = t; k < 512; k += 256) {
        float x = T[3 * (j0 + k) + 0];
        float y = T[3 * (j0 + k) + 1];
        float z = T[3 * (j0 + k) + 2];
        tg[k] = make_float4(x, y, z, x * x + y * y + z * z);
    }
    __syncthreads();
    int q0 = blockIdx.x * 512 + t;          // second query = q0 + 256
    float ax = Q[3 * q0 + 0], ay = Q[3 * q0 + 1], az = Q[3 * q0 + 2];
    float bx = Q[3 * (q0 + 256) + 0], by = Q[3 * (q0 + 256) + 1],
          bz = Q[3 * (q0 + 256) + 2];
    float best0 = 3.4e38f, best1 = 3.4e38f;
    int bj0 = 0, bj1 = 0;
    #pragma unroll 4
    for (int j = 0; j < 512; ++j) {
        float4 f = tg[j];
        float dot0 = ax * f.x + ay * f.y + az * f.z;
        float dot1 = bx * f.x + by * f.y + bz * f.z;
        float d0 = fmaf(-2.0f, dot0, f.w);
        float d1 = fmaf(-2.0f, dot1, f.w);
        if (d0 < best0) { best0 = d0; bj0 = j; }
        if (d1 < best1) { best1 = d1; bj1 = j; }
    }
    int slot0 = ((pass << 4) + blockIdx.y) * 8192 + q0;
    pmin[slot0] = best0;
    pidx[slot0] = j0 + bj0;
    pmin[slot0 + 256] = best1;
    pidx[slot0 + 256] = j0 + bj1;
}

// ---------------------------------------------------------------- NN reduce v2
// folds 16 partials (strict <, in slice order), re-adds rr for the distance.
__global__ __launch_bounds__(256) void dist_reduce_kernel(
    const float* __restrict__ pmin, const int* __restrict__ pidx,
    const float* __restrict__ rp, const float* __restrict__ sp,
    int* __restrict__ idx, float* __restrict__ md) {
    int gid = blockIdx.x * 256 + threadIdx.x;
    int pass = gid >> 13;
    int q = gid & 8191;
    const float* Q = pass ? sp : rp;
    float qx = Q[3 * q + 0], qy = Q[3 * q + 1], qz = Q[3 * q + 2];
    float rr = qx * qx + qy * qy + qz * qz;
    float best = 3.4e38f; int bi = 0;
    #pragma unroll
    for (int s = 0; s < 16; ++s) {
        int slot = ((pass << 4) + s) * 8192 + q;
        float v = pmin[slot];
        if (v < best) { best = v; bi = pidx[slot]; }
    }
    idx[pass * 8192 + q] = bi;
    md[pass * 8192 + q] = sqrtf(fmaxf(best + rr, 1e-12f));
}

// ---------------------------------------------------------------- feat assembly
// wave per row, 4 rows/block, grid 4096. A1 row = [hi(544) | lo(544)],
// cols: fa 0..255, fb 256..511, pa 512..514, pb 515..517, dist 518, score 519,
// pad 520..543 zero.
__global__ __launch_bounds__(256) void feat_assemble_kernel(
    const float* __restrict__ rfeat, const float* __restrict__ sfeat,
    const float* __restrict__ rp, const float* __restrict__ sp,
    const float* __restrict__ invn, const float* __restrict__ stats,
    const int* __restrict__ idx, const float* __restrict__ md,
    unsigned short* __restrict__ A1) {
    int wid = threadIdx.x >> 6, lane = threadIdx.x & 63;
    int i = blockIdx.x * 4 + wid;
    float mx = stats[0], my = stats[1], mz = stats[2], rinv = 1.0f / stats[3];

    const float *fa, *fb, *pA, *pB;
    float inva, invb, dist;
    if (i < NREF) {
        int j = idx[i];
        fa = rfeat + (size_t)i * DF;  fb = sfeat + (size_t)j * DF;
        inva = invn[i];               invb = invn[NREF + j];
        pA = rp + 3 * i;              pB = sp + 3 * j;
        dist = md[i];
    } else {
        int jj = i - NREF;
        int j = idx[NREF + jj];
        fa = sfeat + (size_t)jj * DF; fb = rfeat + (size_t)j * DF;
        inva = invn[NREF + jj];       invb = invn[j];
        pA = sp + 3 * jj;             pB = rp + 3 * j;
        dist = md[NREF + jj];
    }

    float4 a4 = *(const float4*)&fa[lane * 4];
    float4 b4 = *(const float4*)&fb[lane * 4];
    a4.x *= inva; a4.y *= inva; a4.z *= inva; a4.w *= inva;
    b4.x *= invb; b4.y *= invb; b4.z *= invb; b4.w *= invb;
    float d = a4.x * b4.x + a4.y * b4.y + a4.z * b4.z + a4.w * b4.w;
    #pragma unroll
    for (int off = 32; off > 0; off >>= 1) d += __shfl_xor(d, off, 64);

    unsigned short* row = A1 + (size_t)i * KA1;
    ushort4 h, l;
    h.x = f2bf_rn(a4.x); l.x = f2bf_rn(a4.x - bf2f(h.x));
    h.y = f2bf_rn(a4.y); l.y = f2bf_rn(a4.y - bf2f(h.y));
    h.z = f2bf_rn(a4.z); l.z = f2bf_rn(a4.z - bf2f(h.z));
    h.w = f2bf_rn(a4.w); l.w = f2bf_rn(a4.w - bf2f(h.w));
    *(ushort4*)&row[lane * 4] = h;
    *(ushort4*)&row[SPLIT1 + lane * 4] = l;
    h.x = f2bf_rn(b4.x); l.x = f2bf_rn(b4.x - bf2f(h.x));
    h.y = f2bf_rn(b4.y); l.y = f2bf_rn(b4.y - bf2f(h.y));
    h.z = f2bf_rn(b4.z); l.z = f2bf_rn(b4.z - bf2f(h.z));
    h.w = f2bf_rn(b4.w); l.w = f2bf_rn(b4.w - bf2f(h.w));
    *(ushort4*)&row[256 + lane * 4] = h;
    *(ushort4*)&row[SPLIT1 + 256 + lane * 4] = l;

    if (lane < 8) {
        float v;
        if (lane < 3)      v = (&pA[0])[lane];
        else if (lane < 6) v = (&pB[0])[lane - 3];
        else if (lane == 6) v = dist;
        else               v = d;
        if (lane < 3)      v = (v - ((lane == 0) ? mx : (lane == 1) ? my : mz)) * rinv;
        else if (lane < 6) v = (v - ((lane == 3) ? mx : (lane == 4) ? my : mz)) * rinv;
        unsigned short vh = f2bf_rn(v), vl = f2bf_rn(v - bf2f(vh));
        row[512 + lane] = vh;
        row[SPLIT1 + 512 + lane] = vl;
    } else if (lane < 32) {
        row[512 + lane] = 0;
        row[SPLIT1 + 512 + lane] = 0;
    }
}

// ---------------------------------------------------------------- bf16 GEMM
// C = A' @ B'T^T + bias. Logical K (3*SPLIT); A physical [hi|lo] width KA=2*SPLIT:
// kphys = k < SPLIT ? k : k - SPLIT  (aliases logical hi,hi,lo).
__global__ __launch_bounds__(512) void gemm_bf16_bt_kernel(
    const unsigned short* __restrict__ A, const unsigned short* __restrict__ B,
    const float* __restrict__ bias, float* __restrict__ C,
    int N, int K, int KA, int SPLIT) {
    __shared__ unsigned short As[64][40];
    __shared__ unsigned short Bs[256][40];
    const int tid = threadIdx.x;
    const int row0 = blockIdx.x * 64, col0 = blockIdx.y * 256;
    const int lane = tid & 63, wid = tid >> 6;
    const int wr = wid >> 2, wc = wid & 3;
    const int r = lane & 15, kg = lane >> 4;

    const int arow = tid >> 2, achk = tid & 3;
    const int brow = tid >> 1, bhalf = tid & 1;

    f32x4 acc[2][4];
    #pragma unroll
    for (int i = 0; i < 2; ++i)
        #pragma unroll
        for (int j = 0; j < 4; ++j) acc[i][j] = (f32x4){0.f, 0.f, 0.f, 0.f};

    const int ns = K / 32;
    int4 aR = {0, 0, 0, 0}, bR0, bR1;
    if (tid < 256) aR = *(const int4*)&A[(size_t)(row0 + arow) * KA + achk * 8];
    bR0 = *(const int4*)&B[(size_t)(col0 + brow) * K + bhalf * 16];
    bR1 = *(const int4*)&B[(size_t)(col0 + brow) * K + bhalf * 16 + 8];

    for (int kt = 0; kt < ns; ++kt) {
        __syncthreads();
        if (tid < 256) *(int4*)&As[arow][achk * 8] = aR;
        *(int4*)&Bs[brow][bhalf * 16] = bR0;
        *(int4*)&Bs[brow][bhalf * 16 + 8] = bR1;
        __syncthreads();
        if (kt + 1 < ns) {
            int k0 = (kt + 1) * 32;
            int kp = (k0 < SPLIT) ? k0 : k0 - SPLIT;
            if (tid < 256) aR = *(const int4*)&A[(size_t)(row0 + arow) * KA + kp + achk * 8];
            bR0 = *(const int4*)&B[(size_t)(col0 + brow) * K + k0 + bhalf * 16];
            bR1 = *(const int4*)&B[(size_t)(col0 + brow) * K + k0 + bhalf * 16 + 8];
        }
        bf16x8 af[2], bf[4];
        #pragma unroll
        for (int fi = 0; fi < 2; ++fi)
            af[fi] = *(const bf16x8*)&As[wr * 32 + fi * 16 + r][kg * 8];
        #pragma unroll
        for (int fj = 0; fj < 4; ++fj)
            bf[fj] = *(const bf16x8*)&Bs[wc * 64 + fj * 16 + r][kg * 8];
        #pragma unroll
        for (int fi = 0; fi < 2; ++fi)
            #pragma unroll
            for (int fj = 0; fj < 4; ++fj)
                acc[fi][fj] = __builtin_amdgcn_mfma_f32_16x16x32_bf16(
                    af[fi], bf[fj], acc[fi][fj], 0, 0, 0);
    }

    #pragma unroll
    for (int fj = 0; fj < 4; ++fj) {
        int gcol = col0 + wc * 64 + fj * 16 + r;
        float bb = bias[gcol];
        #pragma unroll
        for (int fi = 0; fi < 2; ++fi) {
            int grow = row0 + wr * 32 + fi * 16 + kg * 4;
            #pragma unroll
            for (int i = 0; i < 4; ++i)
                C[(size_t)(grow + i) * N + gcol] = acc[fi][fj][i] + bb;
        }
    }
}

// ---------------------------------------------------------------- instnorm+relu+split (h1 -> A2')
__global__ __launch_bounds__(256) void instnorm_split_kernel(
    const float* __restrict__ h1, unsigned short* __restrict__ A2) {
    int wid = threadIdx.x >> 6, lane = threadIdx.x & 63;
    int row = blockIdx.x * 4 + wid;
    float4 x = *(const float4*)&h1[(size_t)row * 256 + lane * 4];
    float s = x.x + x.y + x.z + x.w;
    float q = x.x * x.x + x.y * x.y + x.z * x.z + x.w * x.w;
    #pragma unroll
    for (int off = 32; off > 0; off >>= 1) {
        s += __shfl_xor(s, off, 64);
        q += __shfl_xor(q, off, 64);
    }
    float m = s * (1.0f / 256.0f);
    float var = q * (1.0f / 256.0f) - m * m;
    float rs = rsqrtf(var + EPSV);
    float y[4] = { fmaxf((x.x - m) * rs, 0.f), fmaxf((x.y - m) * rs, 0.f),
                   fmaxf((x.z - m) * rs, 0.f), fmaxf((x.w - m) * rs, 0.f) };
    ushort4 hi, lo;
    hi.x = f2bf_rn(y[0]); lo.x = f2bf_rn(y[0] - bf2f(hi.x));
    hi.y = f2bf_rn(y[1]); lo.y = f2bf_rn(y[1] - bf2f(hi.y));
    hi.z = f2bf_rn(y[2]); lo.z = f2bf_rn(y[2] - bf2f(hi.z));
    hi.w = f2bf_rn(y[3]); lo.w = f2bf_rn(y[3] - bf2f(hi.w));
    unsigned short* row_p = A2 + (size_t)row * KA2;
    *(ushort4*)&row_p[lane * 4] = hi;
    *(ushort4*)&row_p[SPLIT2 + lane * 4] = lo;
}

// ---------------------------------------------------------------- instnorm+relu+colsum
__global__ __launch_bounds__(256) void instnorm_colsum_kernel(
    const float* __restrict__ h2, float* __restrict__ mbar) {
    __shared__ float cs[512];
    int t = threadIdx.x;
    int wid = t >> 6, lane = t & 63;
    float2 colacc[4] = {{0.f,0.f},{0.f,0.f},{0.f,0.f},{0.f,0.f}};
    #pragma unroll
    for (int rr = 0; rr < 8; ++rr) {
        int row = blockIdx.x * 32 + wid * 8 + rr;
        const float* rp = h2 + (size_t)row * 512;
        float2 xv[4];
        float s = 0.f, q = 0.f;
        #pragma unroll
        for (int j = 0; j < 4; ++j) {
            xv[j] = *(const float2*)&rp[j * 128 + lane * 2];
            s += xv[j].x + xv[j].y;
            q += xv[j].x * xv[j].x + xv[j].y * xv[j].y;
        }
        #pragma unroll
        for (int off = 32; off > 0; off >>= 1) {
            s += __shfl_xor(s, off, 64);
            q += __shfl_xor(q, off, 64);
        }
        float m = s * (1.0f / 512.0f);
        float var = q * (1.0f / 512.0f) - m * m;
        float rs = rsqrtf(var + EPSV);
        #pragma unroll
        for (int j = 0; j < 4; ++j) {
            colacc[j].x += fmaxf((xv[j].x - m) * rs, 0.f);
            colacc[j].y += fmaxf((xv[j].y - m) * rs, 0.f);
        }
    }
    cs[t] = 0.f; cs[t + 256] = 0.f;
    __syncthreads();
    for (int w = 0; w < 4; ++w) {
        if (wid == w) {
            #pragma unroll
            for (int j = 0; j < 4; ++j) {
                cs[j * 128 + lane * 2]     += colacc[j].x;
                cs[j * 128 + lane * 2 + 1] += colacc[j].y;
            }
        }
        __syncthreads();
    }
    atomicAdd(&mbar[t], cs[t]);
    atomicAdd(&mbar[t + 256], cs[t + 256]);
}

// ---------------------------------------------------------------- pooled partial
__global__ __launch_bounds__(256) void pooled_mv_kernel(
    const float* __restrict__ mbar, const float* __restrict__ W3,
    float* __restrict__ pool_raw) {
    int j = blockIdx.x * 256 + threadIdx.x;
    int k0 = blockIdx.y * 32;
    float acc = 0.f;
    #pragma unroll 8
    for (int kk = 0; kk < 32; ++kk)
        acc = fmaf(mbar[k0 + kk], W3[(size_t)(k0 + kk) * 1024 + j], acc);
    atomicAdd(&pool_raw[j], acc * (1.0f / 16384.0f));
}

// ---------------------------------------------------------------- c1 partial
__global__ __launch_bounds__(256) void c1_mv_kernel(
    const float* __restrict__ pool_raw, const float* __restrict__ b3,
    const float* __restrict__ Wc1, float* __restrict__ t1_raw) {
    int o = blockIdx.x * 256 + threadIdx.x;
    int k0 = blockIdx.y * 32;
    float acc = 0.f;
    #pragma unroll 8
    for (int kk = 0; kk < 32; ++kk)
        acc = fmaf(pool_raw[k0 + kk] + b3[k0 + kk],
                   Wc1[(size_t)(k0 + kk) * 512 + o], acc);
    atomicAdd(&t1_raw[o], acc);
}

// ---------------------------------------------------------------- tail
__global__ __launch_bounds__(256) void tail_kernel(
    const float* __restrict__ t1_raw, const float* __restrict__ bc1,
    const float* __restrict__ g1, const float* __restrict__ be1,
    const float* __restrict__ Wc2, const float* __restrict__ bc2,
    const float* __restrict__ g2, const float* __restrict__ be2,
    const float* __restrict__ Wc3, const float* __restrict__ bc3,
    float* __restrict__ out) {
    __shared__ float a1[512];
    __shared__ float a2[256];
    __shared__ float gm[32], gv[32];
    int t = threadIdx.x;
    a1[t] = t1_raw[t] + bc1[t];
    a1[t + 256] = t1_raw[t + 256] + bc1[t + 256];
    __syncthreads();
    if (t < 32) {
        float s = 0.f;
        for (int k = 0; k < 16; ++k) s += a1[t * 16 + k];
        float m = s * (1.0f / 16.0f);
        float q = 0.f;
        for (int k = 0; k < 16; ++k) { float d = a1[t * 16 + k] - m; q += d * d; }
        gm[t] = m;
        gv[t] = rsqrtf(q * (1.0f / 16.0f) + EPSV);
    }
    __syncthreads();
    float v0 = (a1[t] - gm[t >> 4]) * gv[t >> 4];
    float v1 = (a1[t + 256] - gm[(t + 256) >> 4]) * gv[(t + 256) >> 4];
    v0 = fmaxf(fmaf(v0, g1[t], be1[t]), 0.f);
    v1 = fmaxf(fmaf(v1, g1[t + 256], be1[t + 256]), 0.f);
    __syncthreads();
    a1[t] = v0;
    a1[t + 256] = v1;
    __syncthreads();
    float acc = bc2[t];
    #pragma unroll 8
    for (int k = 0; k < 512; ++k) acc = fmaf(a1[k], Wc2[k * 256 + t], acc);
    a2[t] = acc;
    __syncthreads();
    if (t < 32) {
        float s = 0.f;
        for (int k = 0; k < 8; ++k) s += a2[t * 8 + k];
        float m = s * (1.0f / 8.0f);
        float q = 0.f;
        for (int k = 0; k < 8; ++k) { float d = a2[t * 8 + k] - m; q += d * d; }
        gm[t] = m;
        gv[t] = rsqrtf(q * (1.0f / 8.0f) + EPSV);
    }
    __syncthreads();
    float w = (a2[t] - gm[t >> 3]) * gv[t >> 3];
    w = fmaxf(fmaf(w, g2[t], be2[t]), 0.f);
    __syncthreads();
    a2[t] = w;
    __syncthreads();
    if (t < 2) {
        float acc2 = bc3[t];
        #pragma unroll 8
        for (int k = 0; k < 256; ++k) acc2 = fmaf(a2[k], Wc3[k * 2 + t], acc2);
        out[t] = acc2;
    }
}

// ============================================================================
extern "C" void kernel_launch(void* const* d_in, const int* in_sizes, int n_in,
                              void* d_out, int out_size, void* d_ws, size_t ws_size,
                              hipStream_t stream) {
    const float* ref_points = (const float*)d_in[0];
    const float* src_points = (const float*)d_in[1];
    const float* ref_feats  = (const float*)d_in[2];
    const float* src_feats  = (const float*)d_in[3];
    const float* W1  = (const float*)d_in[4];
    const float* b1  = (const float*)d_in[5];
    const float* W2  = (const float*)d_in[6];
    const float* b2  = (const float*)d_in[7];
    const float* W3  = (const float*)d_in[8];
    const float* b3  = (const float*)d_in[9];
    const float* Wc1 = (const float*)d_in[10];
    const float* bc1 = (const float*)d_in[11];
    const float* g1  = (const float*)d_in[12];
    const float* be1 = (const float*)d_in[13];
    const float* Wc2 = (const float*)d_in[14];
    const float* bc2 = (const float*)d_in[15];
    const float* g2  = (const float*)d_in[16];
    const float* be2 = (const float*)d_in[17];
    const float* Wc3 = (const float*)d_in[18];
    const float* bc3 = (const float*)d_in[19];
    float* out = (float*)d_out;

    float* ws = (float*)d_ws;
    unsigned short* A1  = (unsigned short*)(ws + OFF_R);
    unsigned short* A2  = (unsigned short*)(ws + OFF_A2);
    float* h2   = ws + OFF_H2;
    float* invn = ws + OFF_INVN;
    float* stats = ws + OFF_STATS;
    float* psum = stats + 8;
    float* pmax = stats + 200;
    float* pmin = ws + OFF_PMIN;
    int*   pidx = (int*)(ws + OFF_PIDX);
    int*   idx  = (int*)(ws + OFF_IDX);
    float* md   = ws + OFF_MD;
    unsigned short* W1T = (unsigned short*)(ws + OFF_W1T);
    unsigned short* W2T = (unsigned short*)(ws + OFF_W2T);
    float* h1   = ws + OFF_H1;
    float* mbar     = ws + OFF_ZERO;
    float* pool_raw = ws + OFF_ZERO + 512;
    float* t1_raw   = ws + OFF_ZERO + 1536;

    hipMemsetAsync(mbar, 0, 2048 * sizeof(float), stream);

    hipLaunchKernelGGL(prep_w1_kernel, dim3(256), dim3(256), 0, stream, W1, W1T);
    hipLaunchKernelGGL(prep_w2_kernel, dim3(512), dim3(256), 0, stream, W2, W2T);
    hipLaunchKernelGGL(feat_norms_kernel, dim3(4096), dim3(256), 0, stream,
                       ref_feats, src_feats, invn);
    hipLaunchKernelGGL(pts_sum_kernel, dim3(64), dim3(256), 0, stream,
                       ref_points, src_points, psum);
    hipLaunchKernelGGL(pts_max_kernel, dim3(64), dim3(256), 0, stream,
                       ref_points, src_points, psum, pmax);
    hipLaunchKernelGGL(pts_final_kernel, dim3(1), dim3(64), 0, stream,
                       psum, pmax, stats);
    hipLaunchKernelGGL(dist_partial_kernel, dim3(16, 16, 2), dim3(256), 0, stream,
                       ref_points, src_points, pmin, pidx);
    hipLaunchKernelGGL(dist_reduce_kernel, dim3(64), dim3(256), 0, stream,
                       pmin, pidx, ref_points, src_points, idx, md);
    hipLaunchKernelGGL(feat_assemble_kernel, dim3(4096), dim3(256), 0, stream,
                       ref_feats, src_feats, ref_points, src_points,
                       invn, stats, idx, md, A1);
    hipLaunchKernelGGL(gemm_bf16_bt_kernel, dim3(256, 1), dim3(512), 0, stream,
                       A1, W1T, b1, h1, 256, K1X, KA1, SPLIT1);
    hipLaunchKernelGGL(instnorm_split_kernel, dim3(4096), dim3(256), 0, stream, h1, A2);
    hipLaunchKernelGGL(gemm_bf16_bt_kernel, dim3(256, 2), dim3(512), 0, stream,
                       A2, W2T, b2, h2, 512, K2X, KA2, SPLIT2);
    hipLaunchKernelGGL(instnorm_colsum_kernel, dim3(512), dim3(256), 0, stream, h2, mbar);
    hipLaunchKernelGGL(pooled_mv_kernel, dim3(4, 16), dim3(256), 0, stream,
                       mbar, W3, pool_raw);
    hipLaunchKernelGGL(c1_mv_kernel, dim3(2, 32), dim3(256), 0, stream,
                       pool_raw, b3, Wc1, t1_raw);
    hipLaunchKernelGGL(tail_kernel, dim3(1), dim3(256), 0, stream,
                       t1_raw, bc1, g1, be1, Wc2, bc2, g2, be2, Wc3, bc3, out);
}

// Round 13
// 283.396 us; speedup vs baseline: 1.7137x; 1.0158x over previous
//
#include <hip/hip_runtime.h>
#include <math.h>

// ============================================================================
// GeoTransformer head — round 13:
//  - GEMM BN 256->128: grid 512/1024 blocks (2-4 blocks/CU, was 1-2),
//    wave tile 32x32 (acc[2][2]), LDS 15.4KB, __launch_bounds__(512,4).
//  - feat_norms fused into feat_assemble (rows already loaded there).
//  - prep_w1+prep_w2 merged into one launch.
//  - dist_partial v2 (2q/thread) kept from round 12 (48->~34us measured-ish).
//
// ws layout unchanged (invn region now unused).
// ============================================================================

#define NREF 8192
#define NTOT 16384
#define DF   256
#define EPSV 1e-5f

#define SPLIT1 544
#define KA1    1088
#define K1X    1632
#define SPLIT2 256
#define KA2    512
#define K2X    768

#define OFF_R     0u
#define OFF_A2    0u
#define OFF_H2    4194304u
#define OFF_INVN  12582912u
#define OFF_STATS 12599296u
#define OFF_PMIN  12599808u
#define OFF_PIDX  12861952u
#define OFF_IDX   13124096u
#define OFF_MD    13140480u
#define OFF_W1T   13156864u
#define OFF_W2T   13365760u
#define OFF_H1    13562368u
#define OFF_ZERO  17756672u

typedef float f32x4 __attribute__((ext_vector_type(4)));
typedef __bf16 bf16x8 __attribute__((ext_vector_type(8)));

__device__ __forceinline__ unsigned short f2bf_rn(float x) {
    union { float f; unsigned int u; } v; v.f = x;
    unsigned int r = (v.u + 0x7FFFu + ((v.u >> 16) & 1u)) >> 16;
    return (unsigned short)r;
}
__device__ __forceinline__ float bf2f(unsigned short h) {
    union { unsigned int u; float f; } v; v.u = ((unsigned int)h) << 16;
    return v.f;
}

__device__ __forceinline__ float block_reduce_sum(float v, float* sm) {
    int t = threadIdx.x;
    sm[t] = v; __syncthreads();
    for (int s = 128; s > 0; s >>= 1) {
        if (t < s) sm[t] += sm[t + s];
        __syncthreads();
    }
    float r = sm[0]; __syncthreads();
    return r;
}
__device__ __forceinline__ float block_reduce_max(float v, float* sm) {
    int t = threadIdx.x;
    sm[t] = v; __syncthreads();
    for (int s = 128; s > 0; s >>= 1) {
        if (t < s) sm[t] = fmaxf(sm[t], sm[t + s]);
        __syncthreads();
    }
    float r = sm[0]; __syncthreads();
    return r;
}

// ---------------------------------------------------------------- weight prep
// merged: blocks 0..255 -> W1 col n; 256..767 -> W2 col n-256.
// B' layout (3K wide): sections [hi | lo | hi] pairing A logical [hi|hi|lo].
__global__ __launch_bounds__(256) void prep_w_kernel(
    const float* __restrict__ W1, const float* __restrict__ W2,
    unsigned short* __restrict__ W1T, unsigned short* __restrict__ W2T) {
    if (blockIdx.x < 256) {
        int n = blockIdx.x;
        unsigned short* row = W1T + (size_t)n * K1X;
        for (int k = threadIdx.x; k < SPLIT1; k += 256) {
            unsigned short hi = 0, lo = 0;
            if (k < 520) {
                float x = W1[k * 256 + n];
                hi = f2bf_rn(x);
                lo = f2bf_rn(x - bf2f(hi));
            }
            row[k] = hi;
            row[SPLIT1 + k] = lo;
            row[2 * SPLIT1 + k] = hi;
        }
    } else {
        int n = blockIdx.x - 256;
        int k = threadIdx.x;
        float x = W2[k * 512 + n];
        unsigned short hi = f2bf_rn(x);
        unsigned short lo = f2bf_rn(x - bf2f(hi));
        unsigned short* row = W2T + (size_t)n * K2X;
        row[k] = hi;
        row[256 + k] = lo;
        row[512 + k] = hi;
    }
}

// ---------------------------------------------------------------- pts stats
__global__ __launch_bounds__(256) void pts_sum_kernel(
    const float* __restrict__ rp, const float* __restrict__ sp,
    float* __restrict__ psum) {
    __shared__ float sm[256];
    int i = blockIdx.x * 256 + threadIdx.x;
    const float* p = (i < NREF) ? (rp + 3 * i) : (sp + 3 * (i - NREF));
    float sx = block_reduce_sum(p[0], sm);
    float sy = block_reduce_sum(p[1], sm);
    float sz = block_reduce_sum(p[2], sm);
    if (threadIdx.x == 0) {
        psum[blockIdx.x * 3 + 0] = sx;
        psum[blockIdx.x * 3 + 1] = sy;
        psum[blockIdx.x * 3 + 2] = sz;
    }
}

__global__ __launch_bounds__(256) void pts_max_kernel(
    const float* __restrict__ rp, const float* __restrict__ sp,
    const float* __restrict__ psum, float* __restrict__ pmax) {
    __shared__ float sm[256];
    float mx = 0.f, my = 0.f, mz = 0.f;
    for (int k = 0; k < 64; ++k) {
        mx += psum[k * 3 + 0]; my += psum[k * 3 + 1]; mz += psum[k * 3 + 2];
    }
    mx *= (1.0f / NTOT); my *= (1.0f / NTOT); mz *= (1.0f / NTOT);
    int i = blockIdx.x * 256 + threadIdx.x;
    const float* p = (i < NREF) ? (rp + 3 * i) : (sp + 3 * (i - NREF));
    float dx = p[0] - mx, dy = p[1] - my, dz = p[2] - mz;
    float v = block_reduce_max(dx * dx + dy * dy + dz * dz, sm);
    if (threadIdx.x == 0) pmax[blockIdx.x] = v;
}

__global__ __launch_bounds__(64) void pts_final_kernel(
    const float* __restrict__ psum, const float* __restrict__ pmax,
    float* __restrict__ stats) {
    int lane = threadIdx.x;
    float v = pmax[lane];
    #pragma unroll
    for (int off = 32; off > 0; off >>= 1) v = fmaxf(v, __shfl_xor(v, off, 64));
    if (lane == 0) {
        float mx = 0.f, my = 0.f, mz = 0.f;
        for (int k = 0; k < 64; ++k) {
            mx += psum[k * 3 + 0]; my += psum[k * 3 + 1]; mz += psum[k * 3 + 2];
        }
        stats[0] = mx * (1.0f / NTOT);
        stats[1] = my * (1.0f / NTOT);
        stats[2] = mz * (1.0f / NTOT);
        stats[3] = sqrtf(v);
    }
}

// ---------------------------------------------------------------- NN partial v2
// grid (16, 16, 2), 2 queries/thread; comparison excludes rr (re-added later).
__global__ __launch_bounds__(256) void dist_partial_kernel(
    const float* __restrict__ rp, const float* __restrict__ sp,
    float* __restrict__ pmin, int* __restrict__ pidx) {
    __shared__ float4 tg[512];
    int pass = blockIdx.z;
    const float* Q = pass ? sp : rp;
    const float* T = pass ? rp : sp;
    int t = threadIdx.x;
    int j0 = blockIdx.y * 512;
    for (int k = t; k < 512; k += 256) {
        float x = T[3 * (j0 + k) + 0];
        float y = T[3 * (j0 + k) + 1];
        float z = T[3 * (j0 + k) + 2];
        tg[k] = make_float4(x, y, z, x * x + y * y + z * z);
    }
    __syncthreads();
    int q0 = blockIdx.x * 512 + t;
    float ax = Q[3 * q0 + 0], ay = Q[3 * q0 + 1], az = Q[3 * q0 + 2];
    float bx = Q[3 * (q0 + 256) + 0], by = Q[3 * (q0 + 256) + 1],
          bz = Q[3 * (q0 + 256) + 2];
    float best0 = 3.4e38f, best1 = 3.4e38f;
    int bj0 = 0, bj1 = 0;
    #pragma unroll 4
    for (int j = 0; j < 512; ++j) {
        float4 f = tg[j];
        float dot0 = ax * f.x + ay * f.y + az * f.z;
        float dot1 = bx * f.x + by * f.y + bz * f.z;
        float d0 = fmaf(-2.0f, dot0, f.w);
        float d1 = fmaf(-2.0f, dot1, f.w);
        if (d0 < best0) { best0 = d0; bj0 = j; }
        if (d1 < best1) { best1 = d1; bj1 = j; }
    }
    int slot0 = ((pass << 4) + blockIdx.y) * 8192 + q0;
    pmin[slot0] = best0;
    pidx[slot0] = j0 + bj0;
    pmin[slot0 + 256] = best1;
    pidx[slot0 + 256] = j0 + bj1;
}

// ---------------------------------------------------------------- NN reduce v2
__global__ __launch_bounds__(256) void dist_reduce_kernel(
    const float* __restrict__ pmin, const int* __restrict__ pidx,
    const float* __restrict__ rp, const float* __restrict__ sp,
    int* __restrict__ idx, float* __restrict__ md) {
    int gid = blockIdx.x * 256 + threadIdx.x;
    int pass = gid >> 13;
    int q = gid & 8191;
    const float* Q = pass ? sp : rp;
    float qx = Q[3 * q + 0], qy = Q[3 * q + 1], qz = Q[3 * q + 2];
    float rr = qx * qx + qy * qy + qz * qz;
    float best = 3.4e38f; int bi = 0;
    #pragma unroll
    for (int s = 0; s < 16; ++s) {
        int slot = ((pass << 4) + s) * 8192 + q;
        float v = pmin[slot];
        if (v < best) { best = v; bi = pidx[slot]; }
    }
    idx[pass * 8192 + q] = bi;
    md[pass * 8192 + q] = sqrtf(fmaxf(best + rr, 1e-12f));
}

// ---------------------------------------------------------------- feat assembly (+inline norms)
// wave per row, 4 rows/block, grid 4096. Row norms computed in-register from
// the raw feature rows (feat_norms kernel eliminated).
__global__ __launch_bounds__(256) void feat_assemble_kernel(
    const float* __restrict__ rfeat, const float* __restrict__ sfeat,
    const float* __restrict__ rp, const float* __restrict__ sp,
    const float* __restrict__ stats,
    const int* __restrict__ idx, const float* __restrict__ md,
    unsigned short* __restrict__ A1) {
    int wid = threadIdx.x >> 6, lane = threadIdx.x & 63;
    int i = blockIdx.x * 4 + wid;
    float mx = stats[0], my = stats[1], mz = stats[2], rinv = 1.0f / stats[3];

    const float *fa, *fb, *pA, *pB;
    float dist;
    if (i < NREF) {
        int j = idx[i];
        fa = rfeat + (size_t)i * DF;  fb = sfeat + (size_t)j * DF;
        pA = rp + 3 * i;              pB = sp + 3 * j;
        dist = md[i];
    } else {
        int jj = i - NREF;
        int j = idx[NREF + jj];
        fa = sfeat + (size_t)jj * DF; fb = rfeat + (size_t)j * DF;
        pA = sp + 3 * jj;             pB = rp + 3 * j;
        dist = md[NREF + jj];
    }

    float4 a4 = *(const float4*)&fa[lane * 4];
    float4 b4 = *(const float4*)&fb[lane * 4];
    float qa = a4.x * a4.x + a4.y * a4.y + a4.z * a4.z + a4.w * a4.w;
    float qb = b4.x * b4.x + b4.y * b4.y + b4.z * b4.z + b4.w * b4.w;
    #pragma unroll
    for (int off = 32; off > 0; off >>= 1) {
        qa += __shfl_xor(qa, off, 64);
        qb += __shfl_xor(qb, off, 64);
    }
    float inva = 1.0f / fmaxf(sqrtf(qa), 1e-12f);
    float invb = 1.0f / fmaxf(sqrtf(qb), 1e-12f);
    a4.x *= inva; a4.y *= inva; a4.z *= inva; a4.w *= inva;
    b4.x *= invb; b4.y *= invb; b4.z *= invb; b4.w *= invb;
    float d = a4.x * b4.x + a4.y * b4.y + a4.z * b4.z + a4.w * b4.w;
    #pragma unroll
    for (int off = 32; off > 0; off >>= 1) d += __shfl_xor(d, off, 64);

    unsigned short* row = A1 + (size_t)i * KA1;
    ushort4 h, l;
    h.x = f2bf_rn(a4.x); l.x = f2bf_rn(a4.x - bf2f(h.x));
    h.y = f2bf_rn(a4.y); l.y = f2bf_rn(a4.y - bf2f(h.y));
    h.z = f2bf_rn(a4.z); l.z = f2bf_rn(a4.z - bf2f(h.z));
    h.w = f2bf_rn(a4.w); l.w = f2bf_rn(a4.w - bf2f(h.w));
    *(ushort4*)&row[lane * 4] = h;
    *(ushort4*)&row[SPLIT1 + lane * 4] = l;
    h.x = f2bf_rn(b4.x); l.x = f2bf_rn(b4.x - bf2f(h.x));
    h.y = f2bf_rn(b4.y); l.y = f2bf_rn(b4.y - bf2f(h.y));
    h.z = f2bf_rn(b4.z); l.z = f2bf_rn(b4.z - bf2f(h.z));
    h.w = f2bf_rn(b4.w); l.w = f2bf_rn(b4.w - bf2f(h.w));
    *(ushort4*)&row[256 + lane * 4] = h;
    *(ushort4*)&row[SPLIT1 + 256 + lane * 4] = l;

    if (lane < 8) {
        float v;
        if (lane < 3)      v = (&pA[0])[lane];
        else if (lane < 6) v = (&pB[0])[lane - 3];
        else if (lane == 6) v = dist;
        else               v = d;
        if (lane < 3)      v = (v - ((lane == 0) ? mx : (lane == 1) ? my : mz)) * rinv;
        else if (lane < 6) v = (v - ((lane == 3) ? mx : (lane == 4) ? my : mz)) * rinv;
        unsigned short vh = f2bf_rn(v), vl = f2bf_rn(v - bf2f(vh));
        row[512 + lane] = vh;
        row[SPLIT1 + 512 + lane] = vl;
    } else if (lane < 32) {
        row[512 + lane] = 0;
        row[SPLIT1 + 512 + lane] = 0;
    }
}

// ---------------------------------------------------------------- bf16 GEMM (BN=128)
// C = A' @ B'T^T + bias. BM=64, BN=128, BK=32, 8 waves (2x4), 32x32/wave.
// A physical [hi|lo]: kphys = k < SPLIT ? k : k - SPLIT.
__global__ __launch_bounds__(512, 4) void gemm_bf16_bt_kernel(
    const unsigned short* __restrict__ A, const unsigned short* __restrict__ B,
    const float* __restrict__ bias, float* __restrict__ C,
    int N, int K, int KA, int SPLIT) {
    __shared__ unsigned short As[64][40];
    __shared__ unsigned short Bs[128][40];
    const int tid = threadIdx.x;
    const int row0 = blockIdx.x * 64, col0 = blockIdx.y * 128;
    const int lane = tid & 63, wid = tid >> 6;
    const int wr = wid >> 2, wc = wid & 3;      // 2x4 wave grid
    const int r = lane & 15, kg = lane >> 4;

    const int arow = tid >> 2, achk = tid & 3;  // A stage (tid<256): 64r x 4chk
    const int brow = tid >> 2, bchk = tid & 3;  // B stage (all 512): 128r x 4chk

    f32x4 acc[2][2];
    #pragma unroll
    for (int i = 0; i < 2; ++i)
        #pragma unroll
        for (int j = 0; j < 2; ++j) acc[i][j] = (f32x4){0.f, 0.f, 0.f, 0.f};

    const int ns = K / 32;
    int4 aR = {0, 0, 0, 0}, bR;
    if (tid < 256) aR = *(const int4*)&A[(size_t)(row0 + arow) * KA + achk * 8];
    bR = *(const int4*)&B[(size_t)(col0 + brow) * K + bchk * 8];

    for (int kt = 0; kt < ns; ++kt) {
        __syncthreads();
        if (tid < 256) *(int4*)&As[arow][achk * 8] = aR;
        *(int4*)&Bs[brow][bchk * 8] = bR;
        __syncthreads();
        if (kt + 1 < ns) {
            int k0 = (kt + 1) * 32;
            int kp = (k0 < SPLIT) ? k0 : k0 - SPLIT;
            if (tid < 256) aR = *(const int4*)&A[(size_t)(row0 + arow) * KA + kp + achk * 8];
            bR = *(const int4*)&B[(size_t)(col0 + brow) * K + k0 + bchk * 8];
        }
        bf16x8 af[2], bf[2];
        #pragma unroll
        for (int fi = 0; fi < 2; ++fi)
            af[fi] = *(const bf16x8*)&As[wr * 32 + fi * 16 + r][kg * 8];
        #pragma unroll
        for (int fj = 0; fj < 2; ++fj)
            bf[fj] = *(const bf16x8*)&Bs[wc * 32 + fj * 16 + r][kg * 8];
        #pragma unroll
        for (int fi = 0; fi < 2; ++fi)
            #pragma unroll
            for (int fj = 0; fj < 2; ++fj)
                acc[fi][fj] = __builtin_amdgcn_mfma_f32_16x16x32_bf16(
                    af[fi], bf[fj], acc[fi][fj], 0, 0, 0);
    }

    #pragma unroll
    for (int fj = 0; fj < 2; ++fj) {
        int gcol = col0 + wc * 32 + fj * 16 + r;
        float bb = bias[gcol];
        #pragma unroll
        for (int fi = 0; fi < 2; ++fi) {
            int grow = row0 + wr * 32 + fi * 16 + kg * 4;
            #pragma unroll
            for (int i = 0; i < 4; ++i)
                C[(size_t)(grow + i) * N + gcol] = acc[fi][fj][i] + bb;
        }
    }
}

// ---------------------------------------------------------------- instnorm+relu+split (h1 -> A2')
__global__ __launch_bounds__(256) void instnorm_split_kernel(
    const float* __restrict__ h1, unsigned short* __restrict__ A2) {
    int wid = threadIdx.x >> 6, lane = threadIdx.x & 63;
    int row = blockIdx.x * 4 + wid;
    float4 x = *(const float4*)&h1[(size_t)row * 256 + lane * 4];
    float s = x.x + x.y + x.z + x.w;
    float q = x.x * x.x + x.y * x.y + x.z * x.z + x.w * x.w;
    #pragma unroll
    for (int off = 32; off > 0; off >>= 1) {
        s += __shfl_xor(s, off, 64);
        q += __shfl_xor(q, off, 64);
    }
    float m = s * (1.0f / 256.0f);
    float var = q * (1.0f / 256.0f) - m * m;
    float rs = rsqrtf(var + EPSV);
    float y[4] = { fmaxf((x.x - m) * rs, 0.f), fmaxf((x.y - m) * rs, 0.f),
                   fmaxf((x.z - m) * rs, 0.f), fmaxf((x.w - m) * rs, 0.f) };
    ushort4 hi, lo;
    hi.x = f2bf_rn(y[0]); lo.x = f2bf_rn(y[0] - bf2f(hi.x));
    hi.y = f2bf_rn(y[1]); lo.y = f2bf_rn(y[1] - bf2f(hi.y));
    hi.z = f2bf_rn(y[2]); lo.z = f2bf_rn(y[2] - bf2f(hi.z));
    hi.w = f2bf_rn(y[3]); lo.w = f2bf_rn(y[3] - bf2f(hi.w));
    unsigned short* row_p = A2 + (size_t)row * KA2;
    *(ushort4*)&row_p[lane * 4] = hi;
    *(ushort4*)&row_p[SPLIT2 + lane * 4] = lo;
}

// ---------------------------------------------------------------- instnorm+relu+colsum
__global__ __launch_bounds__(256) void instnorm_colsum_kernel(
    const float* __restrict__ h2, float* __restrict__ mbar) {
    __shared__ float cs[512];
    int t = threadIdx.x;
    int wid = t >> 6, lane = t & 63;
    float2 colacc[4] = {{0.f,0.f},{0.f,0.f},{0.f,0.f},{0.f,0.f}};
    #pragma unroll
    for (int rr = 0; rr < 8; ++rr) {
        int row = blockIdx.x * 32 + wid * 8 + rr;
        const float* rp = h2 + (size_t)row * 512;
        float2 xv[4];
        float s = 0.f, q = 0.f;
        #pragma unroll
        for (int j = 0; j < 4; ++j) {
            xv[j] = *(const float2*)&rp[j * 128 + lane * 2];
            s += xv[j].x + xv[j].y;
            q += xv[j].x * xv[j].x + xv[j].y * xv[j].y;
        }
        #pragma unroll
        for (int off = 32; off > 0; off >>= 1) {
            s += __shfl_xor(s, off, 64);
            q += __shfl_xor(q, off, 64);
        }
        float m = s * (1.0f / 512.0f);
        float var = q * (1.0f / 512.0f) - m * m;
        float rs = rsqrtf(var + EPSV);
        #pragma unroll
        for (int j = 0; j < 4; ++j) {
            colacc[j].x += fmaxf((xv[j].x - m) * rs, 0.f);
            colacc[j].y += fmaxf((xv[j].y - m) * rs, 0.f);
        }
    }
    cs[t] = 0.f; cs[t + 256] = 0.f;
    __syncthreads();
    for (int w = 0; w < 4; ++w) {
        if (wid == w) {
            #pragma unroll
            for (int j = 0; j < 4; ++j) {
                cs[j * 128 + lane * 2]     += colacc[j].x;
                cs[j * 128 + lane * 2 + 1] += colacc[j].y;
            }
        }
        __syncthreads();
    }
    atomicAdd(&mbar[t], cs[t]);
    atomicAdd(&mbar[t + 256], cs[t + 256]);
}

// ---------------------------------------------------------------- pooled partial
__global__ __launch_bounds__(256) void pooled_mv_kernel(
    const float* __restrict__ mbar, const float* __restrict__ W3,
    float* __restrict__ pool_raw) {
    int j = blockIdx.x * 256 + threadIdx.x;
    int k0 = blockIdx.y * 32;
    float acc = 0.f;
    #pragma unroll 8
    for (int kk = 0; kk < 32; ++kk)
        acc = fmaf(mbar[k0 + kk], W3[(size_t)(k0 + kk) * 1024 + j], acc);
    atomicAdd(&pool_raw[j], acc * (1.0f / 16384.0f));
}

// ---------------------------------------------------------------- c1 partial
__global__ __launch_bounds__(256) void c1_mv_kernel(
    const float* __restrict__ pool_raw, const float* __restrict__ b3,
    const float* __restrict__ Wc1, float* __restrict__ t1_raw) {
    int o = blockIdx.x * 256 + threadIdx.x;
    int k0 = blockIdx.y * 32;
    float acc = 0.f;
    #pragma unroll 8
    for (int kk = 0; kk < 32; ++kk)
        acc = fmaf(pool_raw[k0 + kk] + b3[k0 + kk],
                   Wc1[(size_t)(k0 + kk) * 512 + o], acc);
    atomicAdd(&t1_raw[o], acc);
}

// ---------------------------------------------------------------- tail
__global__ __launch_bounds__(256) void tail_kernel(
    const float* __restrict__ t1_raw, const float* __restrict__ bc1,
    const float* __restrict__ g1, const float* __restrict__ be1,
    const float* __restrict__ Wc2, const float* __restrict__ bc2,
    const float* __restrict__ g2, const float* __restrict__ be2,
    const float* __restrict__ Wc3, const float* __restrict__ bc3,
    float* __restrict__ out) {
    __shared__ float a1[512];
    __shared__ float a2[256];
    __shared__ float gm[32], gv[32];
    int t = threadIdx.x;
    a1[t] = t1_raw[t] + bc1[t];
    a1[t + 256] = t1_raw[t + 256] + bc1[t + 256];
    __syncthreads();
    if (t < 32) {
        float s = 0.f;
        for (int k = 0; k < 16; ++k) s += a1[t * 16 + k];
        float m = s * (1.0f / 16.0f);
        float q = 0.f;
        for (int k = 0; k < 16; ++k) { float d = a1[t * 16 + k] - m; q += d * d; }
        gm[t] = m;
        gv[t] = rsqrtf(q * (1.0f / 16.0f) + EPSV);
    }
    __syncthreads();
    float v0 = (a1[t] - gm[t >> 4]) * gv[t >> 4];
    float v1 = (a1[t + 256] - gm[(t + 256) >> 4]) * gv[(t + 256) >> 4];
    v0 = fmaxf(fmaf(v0, g1[t], be1[t]), 0.f);
    v1 = fmaxf(fmaf(v1, g1[t + 256], be1[t + 256]), 0.f);
    __syncthreads();
    a1[t] = v0;
    a1[t + 256] = v1;
    __syncthreads();
    float acc = bc2[t];
    #pragma unroll 8
    for (int k = 0; k < 512; ++k) acc = fmaf(a1[k], Wc2[k * 256 + t], acc);
    a2[t] = acc;
    __syncthreads();
    if (t < 32) {
        float s = 0.f;
        for (int k = 0; k < 8; ++k) s += a2[t * 8 + k];
        float m = s * (1.0f / 8.0f);
        float q = 0.f;
        for (int k = 0; k < 8; ++k) { float d = a2[t * 8 + k] - m; q += d * d; }
        gm[t] = m;
        gv[t] = rsqrtf(q * (1.0f / 8.0f) + EPSV);
    }
    __syncthreads();
    float w = (a2[t] - gm[t >> 3]) * gv[t >> 3];
    w = fmaxf(fmaf(w, g2[t], be2[t]), 0.f);
    __syncthreads();
    a2[t] = w;
    __syncthreads();
    if (t < 2) {
        float acc2 = bc3[t];
        #pragma unroll 8
        for (int k = 0; k < 256; ++k) acc2 = fmaf(a2[k], Wc3[k * 2 + t], acc2);
        out[t] = acc2;
    }
}

// ============================================================================
extern "C" void kernel_launch(void* const* d_in, const int* in_sizes, int n_in,
                              void* d_out, int out_size, void* d_ws, size_t ws_size,
                              hipStream_t stream) {
    const float* ref_points = (const float*)d_in[0];
    const float* src_points = (const float*)d_in[1];
    const float* ref_feats  = (const float*)d_in[2];
    const float* src_feats  = (const float*)d_in[3];
    const float* W1  = (const float*)d_in[4];
    const float* b1  = (const float*)d_in[5];
    const float* W2  = (const float*)d_in[6];
    const float* b2  = (const float*)d_in[7];
    const float* W3  = (const float*)d_in[8];
    const float* b3  = (const float*)d_in[9];
    const float* Wc1 = (const float*)d_in[10];
    const float* bc1 = (const float*)d_in[11];
    const float* g1  = (const float*)d_in[12];
    const float* be1 = (const float*)d_in[13];
    const float* Wc2 = (const float*)d_in[14];
    const float* bc2 = (const float*)d_in[15];
    const float* g2  = (const float*)d_in[16];
    const float* be2 = (const float*)d_in[17];
    const float* Wc3 = (const float*)d_in[18];
    const float* bc3 = (const float*)d_in[19];
    float* out = (float*)d_out;

    float* ws = (float*)d_ws;
    unsigned short* A1  = (unsigned short*)(ws + OFF_R);
    unsigned short* A2  = (unsigned short*)(ws + OFF_A2);
    float* h2   = ws + OFF_H2;
    float* stats = ws + OFF_STATS;
    float* psum = stats + 8;
    float* pmax = stats + 200;
    float* pmin = ws + OFF_PMIN;
    int*   pidx = (int*)(ws + OFF_PIDX);
    int*   idx  = (int*)(ws + OFF_IDX);
    float* md   = ws + OFF_MD;
    unsigned short* W1T = (unsigned short*)(ws + OFF_W1T);
    unsigned short* W2T = (unsigned short*)(ws + OFF_W2T);
    float* h1   = ws + OFF_H1;
    float* mbar     = ws + OFF_ZERO;
    float* pool_raw = ws + OFF_ZERO + 512;
    float* t1_raw   = ws + OFF_ZERO + 1536;

    hipMemsetAsync(mbar, 0, 2048 * sizeof(float), stream);

    hipLaunchKernelGGL(prep_w_kernel, dim3(768), dim3(256), 0, stream,
                       W1, W2, W1T, W2T);
    hipLaunchKernelGGL(pts_sum_kernel, dim3(64), dim3(256), 0, stream,
                       ref_points, src_points, psum);
    hipLaunchKernelGGL(pts_max_kernel, dim3(64), dim3(256), 0, stream,
                       ref_points, src_points, psum, pmax);
    hipLaunchKernelGGL(pts_final_kernel, dim3(1), dim3(64), 0, stream,
                       psum, pmax, stats);
    hipLaunchKernelGGL(dist_partial_kernel, dim3(16, 16, 2), dim3(256), 0, stream,
                       ref_points, src_points, pmin, pidx);
    hipLaunchKernelGGL(dist_reduce_kernel, dim3(64), dim3(256), 0, stream,
                       pmin, pidx, ref_points, src_points, idx, md);
    hipLaunchKernelGGL(feat_assemble_kernel, dim3(4096), dim3(256), 0, stream,
                       ref_feats, src_feats, ref_points, src_points,
                       stats, idx, md, A1);
    hipLaunchKernelGGL(gemm_bf16_bt_kernel, dim3(256, 2), dim3(512), 0, stream,
                       A1, W1T, b1, h1, 256, K1X, KA1, SPLIT1);
    hipLaunchKernelGGL(instnorm_split_kernel, dim3(4096), dim3(256), 0, stream, h1, A2);
    hipLaunchKernelGGL(gemm_bf16_bt_kernel, dim3(256, 4), dim3(512), 0, stream,
                       A2, W2T, b2, h2, 512, K2X, KA2, SPLIT2);
    hipLaunchKernelGGL(instnorm_colsum_kernel, dim3(512), dim3(256), 0, stream, h2, mbar);
    hipLaunchKernelGGL(pooled_mv_kernel, dim3(4, 16), dim3(256), 0, stream,
                       mbar, W3, pool_raw);
    hipLaunchKernelGGL(c1_mv_kernel, dim3(2, 32), dim3(256), 0, stream,
                       pool_raw, b3, Wc1, t1_raw);
    hipLaunchKernelGGL(tail_kernel, dim3(1), dim3(256), 0, stream,
                       t1_raw, bc1, g1, be1, Wc2, bc2, g2, be2, Wc3, bc3, out);
}